// Round 10
// baseline (556.350 us; speedup 1.0000x reference)
//
#include <hip/hip_runtime.h>
#include <math.h>

// Problem constants
constexpr int kBS = 32, kM = 128, kNMAT = kBS * kM;         // 4096 (b,m) pairs
constexpr int kDIN = 64, kDOUT = 32, kMSZ = kDOUT * kDOUT;  // 1024 floats per 32x32
constexpr int kNSweep = 5;  // 4 sweeps -> absmax 0.0156 (marginal); 5 -> 0.0039. Keep 5.

// ws layout (floats):
//   P/log : [3][4096][1024]  (Q=0,K=1,V=2; overwritten in place by logs)
//   sumsq : [3][4096]        (||log||_F^2 per matrix)
//   attn  : [32][128][128]
// mean_log reuses the logQ region (dead after k_attn).
constexpr size_t OFF_SS   = (size_t)3 * kNMAT * kMSZ;
constexpr size_t OFF_ATTN = OFF_SS + (size_t)3 * kNMAT;

#define F4(p)  (*(float4*)(p))
#define CF4(p) (*(const float4*)(p))

// ---------------------------------------------------------------- bimap ----
// P_t = W_t^T X W_t for t in {Q,K,V}; one block per (b,m).
__global__ __launch_bounds__(256) void k_bimap(
    const float* __restrict__ x, const float* __restrict__ Wq,
    const float* __restrict__ Wk, const float* __restrict__ Wv,
    float* __restrict__ P) {
  __shared__ float Xs[64 * 68];   // X, row-major padded
  __shared__ float Wsh[64 * 32];  // current W, row-major
  __shared__ float Ts[64 * 36];   // T = X*W, padded
  const int t = threadIdx.x;
  const int bm = blockIdx.x;
  const float* xp = x + (size_t)bm * (kDIN * kDIN);
  {
    const int f0 = t * 16;
    const int r = f0 >> 6, c = f0 & 63;
    const float* src = xp + f0;
    float* dst = &Xs[r * 68 + c];
#pragma unroll
    for (int i = 0; i < 4; ++i) F4(dst + 4 * i) = CF4(src + 4 * i);
  }
  const int r0 = (t >> 3) * 2;   // stage-1 rows
  const int j0 = (t & 7) * 4;    // output cols
  const int i2 = t >> 3;         // stage-2 row
  for (int tt = 0; tt < 3; ++tt) {
    const float* W = (tt == 0) ? Wq : ((tt == 1) ? Wk : Wv);
    __syncthreads();  // protect Wsh/Ts from previous type (also covers Xs @ tt=0)
    F4(&Wsh[t * 8]) = CF4(W + t * 8);
    F4(&Wsh[t * 8 + 4]) = CF4(W + t * 8 + 4);
    __syncthreads();
    // stage 1: T = X * W   (64x32). X symmetric: X[r0][k] = Xs[k][r0] -> b64.
    float a0[4] = {0.f, 0.f, 0.f, 0.f}, a1[4] = {0.f, 0.f, 0.f, 0.f};
    for (int k = 0; k < 64; ++k) {
      const float2 x01 = *(const float2*)&Xs[k * 68 + r0];
      const float4 w = CF4(&Wsh[k * 32 + j0]);
      a0[0] += x01.x * w.x; a0[1] += x01.x * w.y; a0[2] += x01.x * w.z; a0[3] += x01.x * w.w;
      a1[0] += x01.y * w.x; a1[1] += x01.y * w.y; a1[2] += x01.y * w.z; a1[3] += x01.y * w.w;
    }
    F4(&Ts[r0 * 36 + j0])       = make_float4(a0[0], a0[1], a0[2], a0[3]);
    F4(&Ts[(r0 + 1) * 36 + j0]) = make_float4(a1[0], a1[1], a1[2], a1[3]);
    __syncthreads();
    // stage 2: P = W^T * T  (32x32)
    float b4[4] = {0.f, 0.f, 0.f, 0.f};
    for (int p = 0; p < 64; ++p) {
      const float wv = Wsh[p * 32 + i2];
      const float4 tv = CF4(&Ts[p * 36 + j0]);
      b4[0] += wv * tv.x; b4[1] += wv * tv.y; b4[2] += wv * tv.z; b4[3] += wv * tv.w;
    }
    F4(&P[((size_t)tt * kNMAT + bm) * kMSZ + i2 * 32 + j0]) =
        make_float4(b4[0], b4[1], b4[2], b4[3]);
  }
}

// ----------------------------------------------------- one-sided Jacobi ----
// Register-resident Brent-Luk one-sided Jacobi, TWO matrices per wave
// (mat = lane>>5), g = lane&15 (pair group), sub = (lane>>4)&1 (row half,
// 16 elems/lane as 8 float2 to invite v_pk_fma_f32 packing).
// 6144 waves = 6 waves/SIMD; LDS = ONE epilogue slot per wave (18.9 KB/block)
// -> 6 blocks/CU fit -> SINGLE dispatch pass (R5's 37.9 KB slot layout capped
// at 4 blocks/CU -> 1.5 passes with a half-empty tail).
// Exchange uses the dead-`old` in-place DPP pattern (every updpp's old
// operand is a dead register, so the allocator ties dest in-place: 4 instr
// per element, no temps, fewer DPP-source-hazard movs):
//   tv = is_g15 ? nq : cq;        // cq dead -> reuse its register
//   tv = updpp<shl1>(tv, np);     // g<=14: np[g+1], g15: nq
//   cp = is_g0 ? np : tv;
//   cq = updpp<shr1>(tv, nq);     // g>=1: nq[g-1], g0: tv(=np[1])
constexpr int kJSlot = 32 * 36 + 32;  // 1152 col data + 32 weights = 1184 floats
constexpr int kShl1 = 0x101, kShr1 = 0x111;

template <int CTRL>
__device__ __forceinline__ float updppf(float old_, float x) {
  return __builtin_bit_cast(float,
      __builtin_amdgcn_update_dpp(__builtin_bit_cast(int, old_),
                                  __builtin_bit_cast(int, x),
                                  CTRL, 0xf, 0xf, false));
}

__device__ __forceinline__ float xsign(float x, float s) {  // x * sgn(s)
  return __builtin_bit_cast(float,
      __builtin_bit_cast(int, x) ^
      (__builtin_bit_cast(int, s) & 0x80000000));
}

__global__ __launch_bounds__(256, 6) void k_jacobi_log(float* __restrict__ P,
                                                       float* __restrict__ sq) {
  __shared__ float lds[4 * kJSlot];  // ONE slot per wave, reused per matrix
  const int t = threadIdx.x;
  const int wid = t >> 6, lane = t & 63;
  const int mat = lane >> 5;         // which of the wave's 2 matrices
  const int g = lane & 15;           // pair group
  const int sub = (lane >> 4) & 1;   // row half
  const int off = sub * 16;

  const bool is_g0 = (g == 0);
  const bool is_g15 = (g == 15);
  // initial columns: g==0 -> {31, 0}; else {g, 31-g}
  const int p0 = is_g0 ? 31 : g;
  const int q0 = is_g0 ? 0 : 31 - g;

  const size_t gbase = (size_t)blockIdx.x * 8 + wid * 2;
  const float* A = P + (gbase + mat) * kMSZ;

  float2 cp2[8], cq2[8];
  {  // A is symmetric: column c == row c (row-major, 32 floats)
    const float* pr = A + p0 * 32 + off;
    const float* qr = A + q0 * 32 + off;
#pragma unroll
    for (int i = 0; i < 16; i += 4) {
      const float4 a = CF4(pr + i);
      cp2[i / 2]     = make_float2(a.x, a.y);
      cp2[i / 2 + 1] = make_float2(a.z, a.w);
      const float4 b = CF4(qr + i);
      cq2[i / 2]     = make_float2(b.x, b.y);
      cq2[i / 2 + 1] = make_float2(b.z, b.w);
    }
  }
  // initial squared norms (pairwise chains, then cross-sub reduce via xor16)
  float app, aqq;
  {
    float2 pa, qa;
    pa.x = cp2[0].x * cp2[0].x;  pa.y = cp2[0].y * cp2[0].y;
    qa.x = cq2[0].x * cq2[0].x;  qa.y = cq2[0].y * cq2[0].y;
#pragma unroll
    for (int j = 1; j < 8; ++j) {
      pa.x = fmaf(cp2[j].x, cp2[j].x, pa.x);
      pa.y = fmaf(cp2[j].y, cp2[j].y, pa.y);
      qa.x = fmaf(cq2[j].x, cq2[j].x, qa.x);
      qa.y = fmaf(cq2[j].y, cq2[j].y, qa.y);
    }
    app = pa.x + pa.y;
    aqq = qa.x + qa.y;
  }
  app += __shfl_xor(app, 16);
  aqq += __shfl_xor(aqq, 16);

  for (int sw = 0; sw < kNSweep; ++sw) {
    for (int r = 0; r < 31; ++r) {
      // apq = colp . colq (two float2 chains, then cross-sub reduce)
      float2 dA, dB;
      dA.x = cp2[0].x * cq2[0].x;  dA.y = cp2[0].y * cq2[0].y;
      dB.x = cp2[1].x * cq2[1].x;  dB.y = cp2[1].y * cq2[1].y;
#pragma unroll
      for (int j = 2; j < 8; j += 2) {
        dA.x = fmaf(cp2[j].x, cq2[j].x, dA.x);
        dA.y = fmaf(cp2[j].y, cq2[j].y, dA.y);
        dB.x = fmaf(cp2[j + 1].x, cq2[j + 1].x, dB.x);
        dB.y = fmaf(cp2[j + 1].y, cq2[j + 1].y, dB.y);
      }
      float apq = (dA.x + dA.y) + (dB.x + dB.y);
      apq += __shfl_xor(apq, 16);
      // rotation from (d, apq) with 3 transcendentals:
      //   h = sqrt(d^2 + 4 apq^2); t = sgn(d) * 2 apq / (|d| + h)
      //   c = rsq(1+t^2); s = t*c.   apq==0 -> t=0 -> exact identity.
      const float d = aqq - app;
      const float apq2 = 2.f * apq;
      float h2 = fmaf(d, d, apq2 * apq2);
      h2 = fmaxf(h2, 1e-38f);  // guard d=apq=0
      const float hr = __builtin_amdgcn_rsqf(h2);
      const float h = h2 * hr;
      const float den = fabsf(d) + h;
      const float t0 = apq2 * __builtin_amdgcn_rcpf(den);
      const float tt = xsign(t0, d);
      const float c = __builtin_amdgcn_rsqf(fmaf(tt, tt, 1.f));
      const float sn = tt * c;
      // fused rotate + in-place-dpp ring exchange, per component
#pragma unroll
      for (int j = 0; j < 8; ++j) {
        {
          const float cpc = cp2[j].x, cqc = cq2[j].x;
          const float np_ = fmaf(-sn, cqc, c * cpc);
          const float nq_ = fmaf(c, cqc, sn * cpc);
          float tv = is_g15 ? nq_ : cqc;
          tv = updppf<kShl1>(tv, np_);
          cp2[j].x = is_g0 ? np_ : tv;
          cq2[j].x = updppf<kShr1>(tv, nq_);
        }
        {
          const float cpc = cp2[j].y, cqc = cq2[j].y;
          const float np_ = fmaf(-sn, cqc, c * cpc);
          const float nq_ = fmaf(c, cqc, sn * cpc);
          float tv = is_g15 ? nq_ : cqc;
          tv = updppf<kShl1>(tv, np_);
          cp2[j].y = is_g0 ? np_ : tv;
          cq2[j].y = updppf<kShr1>(tv, nq_);
        }
      }
      // analytic norm update (rotation preserves app+aqq), flows with columns
      const float c2 = c * c, s2 = sn * sn, cs2 = 2.f * c * sn;
      const float capp = fmaf(c2, app, fmaf(s2, aqq, -cs2 * apq));
      const float caqq = (app + aqq) - capp;
      float tn = is_g15 ? caqq : app;  // app dead
      tn = updppf<kShl1>(tn, capp);
      app = is_g0 ? capp : tn;
      aqq = updppf<kShr1>(tn, caqq);
    }
  }
  // ---- epilogue ----
  // exact column norms in-register (this lane's half + partner's half)
  float ssp, ssq;
  {
    float2 pa, qa;
    pa.x = cp2[0].x * cp2[0].x;  pa.y = cp2[0].y * cp2[0].y;
    qa.x = cq2[0].x * cq2[0].x;  qa.y = cq2[0].y * cq2[0].y;
#pragma unroll
    for (int j = 1; j < 8; ++j) {
      pa.x = fmaf(cp2[j].x, cp2[j].x, pa.x);
      pa.y = fmaf(cp2[j].y, cp2[j].y, pa.y);
      qa.x = fmaf(cq2[j].x, cq2[j].x, qa.x);
      qa.y = fmaf(cq2[j].y, cq2[j].y, qa.y);
    }
    ssp = pa.x + pa.y;
    ssq = qa.x + qa.y;
  }
  ssp += __shfl_xor(ssp, 16);
  ssq += __shfl_xor(ssq, 16);
  const float lgp = 0.5f * logf(ssp);   // log sigma_p
  const float lgq = 0.5f * logf(ssq);
  const float wp = lgp * __builtin_amdgcn_rcpf(ssp);
  const float wq = lgq * __builtin_amdgcn_rcpf(ssq);
  {  // sumsq = sum over pairs (lgp^2 + lgq^2); reduce over g within 16-row
    float tot = fmaf(lgp, lgp, lgq * lgq);
    tot += __shfl_xor(tot, 1); tot += __shfl_xor(tot, 2);
    tot += __shfl_xor(tot, 4); tot += __shfl_xor(tot, 8);
    if ((lane & 31) == 0) sq[gbase + mat] = tot;
  }
  // sequential per-matrix epilogue: half-wave m dumps its columns+weights to
  // the wave's LDS slot, then the FULL wave computes log A = B diag(w) B^T.
  float* Bs = lds + wid * kJSlot;
  float* ncol = Bs + 1152;
  for (int m = 0; m < 2; ++m) {
    __builtin_amdgcn_wave_barrier();
    if (mat == m) {
#pragma unroll
      for (int i = 0; i < 16; i += 4) {
        F4(&Bs[p0 * 36 + off + i]) = make_float4(cp2[i/2].x, cp2[i/2].y,
                                                 cp2[i/2+1].x, cp2[i/2+1].y);
        F4(&Bs[q0 * 36 + off + i]) = make_float4(cq2[i/2].x, cq2[i/2].y,
                                                 cq2[i/2+1].x, cq2[i/2+1].y);
      }
      if (sub == 0) {
        ncol[p0] = wp;
        ncol[q0] = wq;
      }
    }
    __builtin_amdgcn_wave_barrier();
    {  // log A = B diag(w) B^T, 4x4 tile per lane, write back (row-major)
      float* Am = P + (gbase + m) * kMSZ;
      const int rr = (lane >> 3) * 4, cc = (lane & 7) * 4;
      float acc[4][4] = {};
      for (int c = 0; c < 32; ++c) {
        const float w = ncol[c];
        const float4 br = CF4(&Bs[c * 36 + rr]);
        const float4 bc = CF4(&Bs[c * 36 + cc]);
        const float wr[4]  = {w * br.x, w * br.y, w * br.z, w * br.w};
        const float bcv[4] = {bc.x, bc.y, bc.z, bc.w};
#pragma unroll
        for (int i = 0; i < 4; ++i)
#pragma unroll
          for (int j2 = 0; j2 < 4; ++j2) acc[i][j2] += wr[i] * bcv[j2];
      }
#pragma unroll
      for (int i = 0; i < 4; ++i)
        F4(&Am[(rr + i) * 32 + cc]) =
            make_float4(acc[i][0], acc[i][1], acc[i][2], acc[i][3]);
    }
    __builtin_amdgcn_wave_barrier();
  }
}

// ------------------------------------------------- scores/softmax/attn ----
// Block: (jt, b), 16-wide j tile -> 256 blocks (1/CU). K-chunk staged
// TRANSPOSED [k][i] so i-fragments are ds_read_b128; Q [k][j] -> b64.
__global__ __launch_bounds__(256) void k_attn(
    const float* __restrict__ P, const float* __restrict__ sq,
    float* __restrict__ attn) {
  __shared__ float Kt[32 * 132];   // [k][i], padded
  __shared__ float Qt[32 * 20];    // [k][j], padded
  __shared__ float Ss[128 * 20];   // scores [i][j]
  __shared__ float red[16 * 20];
  __shared__ float mcol[16];
  __shared__ float scol[16];
  const int t = threadIdx.x;
  const int b = blockIdx.y, jt = blockIdx.x;
  const int j0g = jt * 16;
  const float* logK = P + ((size_t)kNMAT + (size_t)b * kM) * kMSZ;
  const float* logQ = P + ((size_t)b * kM + j0g) * kMSZ;
  const int i0 = (t >> 3) * 4, j0 = (t & 7) * 2;
  float acc[4][2] = {};
  for (int dc = 0; dc < kMSZ; dc += 32) {
    __syncthreads();
    {  // stage Kt[k][i]: row r of logK, cols dc+c0..+15, transposed write
      const int r = t >> 1, c0 = (t & 1) * 16;
      const float* src = logK + (size_t)r * kMSZ + dc + c0;
#pragma unroll
      for (int ii = 0; ii < 16; ii += 4) {
        const float4 v = CF4(src + ii);
        Kt[(c0 + ii + 0) * 132 + r] = v.x;
        Kt[(c0 + ii + 1) * 132 + r] = v.y;
        Kt[(c0 + ii + 2) * 132 + r] = v.z;
        Kt[(c0 + ii + 3) * 132 + r] = v.w;
      }
    }
    {  // stage Qt[k][j]
      const int j = t >> 4, c0 = (t & 15) * 2;
      const float2 v = *(const float2*)(logQ + (size_t)j * kMSZ + dc + c0);
      Qt[(c0 + 0) * 20 + j] = v.x;
      Qt[(c0 + 1) * 20 + j] = v.y;
    }
    __syncthreads();
    for (int k = 0; k < 32; ++k) {
      const float4 kv = CF4(&Kt[k * 132 + i0]);
      const float2 qv = *(const float2*)&Qt[k * 20 + j0];
      acc[0][0] = fmaf(kv.x, qv.x, acc[0][0]);
      acc[0][1] = fmaf(kv.x, qv.y, acc[0][1]);
      acc[1][0] = fmaf(kv.y, qv.x, acc[1][0]);
      acc[1][1] = fmaf(kv.y, qv.y, acc[1][1]);
      acc[2][0] = fmaf(kv.z, qv.x, acc[2][0]);
      acc[2][1] = fmaf(kv.z, qv.y, acc[2][1]);
      acc[3][0] = fmaf(kv.w, qv.x, acc[3][0]);
      acc[3][1] = fmaf(kv.w, qv.y, acc[3][1]);
    }
  }
  {  // energy -> scores, into Ss[i][j]
    float k2v[4], q2v[2];
#pragma unroll
    for (int i = 0; i < 4; ++i) k2v[i] = sq[kNMAT + b * kM + i0 + i];
#pragma unroll
    for (int j2 = 0; j2 < 2; ++j2) q2v[j2] = sq[b * kM + j0g + j0 + j2];
#pragma unroll
    for (int i = 0; i < 4; ++i)
#pragma unroll
      for (int j2 = 0; j2 < 2; ++j2) {
        float e = k2v[i] + q2v[j2] - 2.f * acc[i][j2];
        e = fmaxf(e, 0.f);
        Ss[(i0 + i) * 20 + (j0 + j2)] = 1.f / (1.f + log1pf(e));
      }
  }
  __syncthreads();
  const int jl = t & 15, grp = t >> 4;  // 16 groups x 16 j-cols; group: 8 i-rows
  {
    float m = -1e30f;
#pragma unroll
    for (int i = 0; i < 8; ++i) m = fmaxf(m, Ss[(grp * 8 + i) * 20 + jl]);
    red[grp * 20 + jl] = m;
  }
  __syncthreads();
  if (t < 16) {
    float m = red[t];
#pragma unroll
    for (int g = 1; g < 16; ++g) m = fmaxf(m, red[g * 20 + t]);
    mcol[t] = m;
  }
  __syncthreads();
  {
    const float mj = mcol[jl];
    float s = 0.f;
#pragma unroll
    for (int i = 0; i < 8; ++i) s += expf(Ss[(grp * 8 + i) * 20 + jl] - mj);
    red[grp * 20 + jl] = s;
  }
  __syncthreads();
  if (t < 16) {
    float s = red[t];
#pragma unroll
    for (int g = 1; g < 16; ++g) s += red[g * 20 + t];
    scol[t] = 1.f / s;
  }
  __syncthreads();
  {  // write attn[b][j][i], coalesced in i
    const int il = t & 31, jg = t >> 5;
#pragma unroll
    for (int rep = 0; rep < 2; ++rep) {
      const int j2 = jg + rep * 8;
      const float mj = mcol[j2], is = scol[j2];
      float* dst = attn + ((size_t)b * kM + j0g + j2) * kM;
#pragma unroll
      for (int c4 = 0; c4 < 4; ++c4) {
        const int i = il + c4 * 32;
        dst[i] = expf(Ss[i * 20 + j2] - mj) * is;
      }
    }
  }
}

// -------------------------------------------------------------- meanlog ----
// ML[b][j][:] = sum_i attn[b][j][i] * logV[b][i][:]. Block: (jt, b), 16 j.
// All 16 j-accumulators in registers (thread owns 4 d-cols); attn weights
// broadcast from LDS (b128 per 4k); V streamed from global (L2-resident).
__global__ __launch_bounds__(256) void k_meanlog(
    const float* __restrict__ attn, const float* __restrict__ P,
    float* __restrict__ ML) {
  __shared__ float As[16 * 132];
  const int t = threadIdx.x;
  const int b = blockIdx.y, jt = blockIdx.x;
  const int j0g = jt * 16;
  const float* logV = P + ((size_t)2 * kNMAT + (size_t)b * kM) * kMSZ;
  {  // stage attn tile [16][128]
    const int j = t >> 4, k0 = (t & 15) * 8;
    const float* src = attn + ((size_t)b * kM + j0g + j) * kM + k0;
    F4(&As[j * 132 + k0])     = CF4(src);
    F4(&As[j * 132 + k0 + 4]) = CF4(src + 4);
  }
  __syncthreads();
  const int d0 = t * 4;
  float acc[16][4] = {};
  for (int k = 0; k < kM; k += 4) {
    float4 vr[4];
#pragma unroll
    for (int kk = 0; kk < 4; ++kk)
      vr[kk] = CF4(&logV[(size_t)(k + kk) * kMSZ + d0]);
#pragma unroll
    for (int j = 0; j < 16; ++j) {
      const float4 w = CF4(&As[j * 132 + k]);
      const float wv[4] = {w.x, w.y, w.z, w.w};
#pragma unroll
      for (int kk = 0; kk < 4; ++kk) {
        const float* vv = (const float*)&vr[kk];
#pragma unroll
        for (int dd = 0; dd < 4; ++dd)
          acc[j][dd] = fmaf(wv[kk], vv[dd], acc[j][dd]);
      }
    }
  }
#pragma unroll
  for (int j = 0; j < 16; ++j)
    F4(&ML[((size_t)b * kM + j0g + j) * kMSZ + d0]) =
        make_float4(acc[j][0], acc[j][1], acc[j][2], acc[j][3]);
}

// ------------------------------------------------------------------ exp ----
// out = exp(S): scaling-and-squaring + degree-7 Horner Taylor (||M||<=0.5
// after scaling -> truncation 1.6e-7, invisible vs the 0.0039 floor).
// 4 waves/block, one matrix per wave, private LDS slot, no s_barrier.
// M and T are SYMMETRIC, so row-fragments load as b128 from [k][r].
constexpr int kESlot = 2 * 1152;  // Mb + Tb

__global__ __launch_bounds__(256) void k_expm(const float* __restrict__ ML,
                                              float* __restrict__ out) {
  __shared__ float lds[4 * kESlot];
  const int t = threadIdx.x;
  const int wid = t >> 6, lane = t & 63;
  const size_t bm = (size_t)blockIdx.x * 4 + wid;
  float* Mb = lds + wid * kESlot;
  float* Tb = Mb + 1152;
  const float* S = ML + bm * kMSZ;
  const int r = lane >> 1, c0 = (lane & 1) * 16;
  float4 v0 = CF4(S + r * 32 + c0),     v1 = CF4(S + r * 32 + c0 + 4),
         v2 = CF4(S + r * 32 + c0 + 8), v3 = CF4(S + r * 32 + c0 + 12);
  float lsum = v0.x*v0.x + v0.y*v0.y + v0.z*v0.z + v0.w*v0.w
             + v1.x*v1.x + v1.y*v1.y + v1.z*v1.z + v1.w*v1.w
             + v2.x*v2.x + v2.y*v2.y + v2.z*v2.z + v2.w*v2.w
             + v3.x*v3.x + v3.y*v3.y + v3.z*v3.z + v3.w*v3.w;
#pragma unroll
  for (int d = 1; d < 64; d <<= 1) lsum += __shfl_xor(lsum, d);
  const float fn = sqrtf(lsum);     // Frobenius norm >= spectral norm
  int sc = 0;
  if (fn > 0.5f) sc = (int)ceilf(log2f(fn * 2.0f));
  const float scale = exp2f((float)(-sc));
  v0.x*=scale; v0.y*=scale; v0.z*=scale; v0.w*=scale;
  v1.x*=scale; v1.y*=scale; v1.z*=scale; v1.w*=scale;
  v2.x*=scale; v2.y*=scale; v2.z*=scale; v2.w*=scale;
  v3.x*=scale; v3.y*=scale; v3.z*=scale; v3.w*=scale;
  F4(&Mb[r * 36 + c0])      = v0;
  F4(&Mb[r * 36 + c0 + 4])  = v1;
  F4(&Mb[r * 36 + c0 + 8])  = v2;
  F4(&Mb[r * 36 + c0 + 12]) = v3;
  __builtin_amdgcn_wave_barrier();
  const int rr = (lane >> 3) * 4, cc = (lane & 7) * 4;
#pragma unroll
  for (int i = 0; i < 4; ++i) {  // T = I + M/7
    float4 v = F4(&Mb[(rr + i) * 36 + cc]);
    v.x = v.x * (1.f/7.f) + ((rr + i == cc + 0) ? 1.f : 0.f);
    v.y = v.y * (1.f/7.f) + ((rr + i == cc + 1) ? 1.f : 0.f);
    v.z = v.z * (1.f/7.f) + ((rr + i == cc + 2) ? 1.f : 0.f);
    v.w = v.w * (1.f/7.f) + ((rr + i == cc + 3) ? 1.f : 0.f);
    F4(&Tb[(rr + i) * 36 + cc]) = v;
  }
  __builtin_amdgcn_wave_barrier();
  for (int j = 6; j >= 1; --j) {  // T <- I + (M*T)/j, in place
    float a4[4][4] = {};
    for (int k = 0; k < 32; ++k) {
      const float4 mv = CF4(&Mb[k * 36 + rr]);  // M[rr..rr+3][k] by symmetry
      const float mvv[4] = {mv.x, mv.y, mv.z, mv.w};
      const float4 tv = CF4(&Tb[k * 36 + cc]);
      const float tvv[4] = {tv.x, tv.y, tv.z, tv.w};
#pragma unroll
      for (int i = 0; i < 4; ++i)
#pragma unroll
        for (int j2 = 0; j2 < 4; ++j2) a4[i][j2] += mvv[i] * tvv[j2];
    }
    const float inv = 1.f / (float)j;
#pragma unroll
    for (int i = 0; i < 4; ++i) {
      float4 v;
      v.x = a4[i][0] * inv + ((rr + i == cc + 0) ? 1.f : 0.f);
      v.y = a4[i][1] * inv + ((rr + i == cc + 1) ? 1.f : 0.f);
      v.z = a4[i][2] * inv + ((rr + i == cc + 2) ? 1.f : 0.f);
      v.w = a4[i][3] * inv + ((rr + i == cc + 3) ? 1.f : 0.f);
      F4(&Tb[(rr + i) * 36 + cc]) = v;
    }
    __builtin_amdgcn_wave_barrier();
  }
  for (int st = 0; st < sc; ++st) {  // T <- T*T, in place (T symmetric)
    float a4[4][4] = {};
    for (int k = 0; k < 32; ++k) {
      const float4 mv = CF4(&Tb[k * 36 + rr]);  // T[rr..rr+3][k] by symmetry
      const float mvv[4] = {mv.x, mv.y, mv.z, mv.w};
      const float4 tv = CF4(&Tb[k * 36 + cc]);
      const float tvv[4] = {tv.x, tv.y, tv.z, tv.w};
#pragma unroll
      for (int i = 0; i < 4; ++i)
#pragma unroll
        for (int j2 = 0; j2 < 4; ++j2) a4[i][j2] += mvv[i] * tvv[j2];
    }
#pragma unroll
    for (int i = 0; i < 4; ++i)
      F4(&Tb[(rr + i) * 36 + cc]) =
          make_float4(a4[i][0], a4[i][1], a4[i][2], a4[i][3]);
    __builtin_amdgcn_wave_barrier();
  }
#pragma unroll
  for (int i = 0; i < 4; ++i) {
    const float4 v = CF4(&Tb[(rr + i) * 36 + cc]);
    F4(&out[bm * kMSZ + (rr + i) * 32 + cc]) = v;
  }
}

// -------------------------------------------------------------- launch ----
extern "C" void kernel_launch(void* const* d_in, const int* in_sizes, int n_in,
                              void* d_out, int out_size, void* d_ws, size_t ws_size,
                              hipStream_t stream) {
  const float* x  = (const float*)d_in[0];
  const float* Wq = (const float*)d_in[1];
  const float* Wk = (const float*)d_in[2];
  const float* Wv = (const float*)d_in[3];
  float* ws   = (float*)d_ws;
  float* P    = ws;                 // [3][4096][1024]
  float* sq   = ws + OFF_SS;        // [3][4096]
  float* attn = ws + OFF_ATTN;      // [32][128][128]
  float* ML   = ws;                 // reuse logQ region (dead after k_attn)
  float* out  = (float*)d_out;

  k_bimap<<<kNMAT, 256, 0, stream>>>(x, Wq, Wk, Wv, P);
  k_jacobi_log<<<3 * kNMAT / 8, 256, 0, stream>>>(P, sq);
  k_attn<<<dim3(8, kBS), 256, 0, stream>>>(P, sq, attn);
  k_meanlog<<<dim3(8, kBS), 256, 0, stream>>>(attn, P, ML);
  k_expm<<<kNMAT / 4, 256, 0, stream>>>(ML, out);
}

// Round 11
// 526.188 us; speedup vs baseline: 1.0573x; 1.0573x over previous
//
#include <hip/hip_runtime.h>
#include <math.h>

// Problem constants
constexpr int kBS = 32, kM = 128, kNMAT = kBS * kM;         // 4096 (b,m) pairs
constexpr int kDIN = 64, kDOUT = 32, kMSZ = kDOUT * kDOUT;  // 1024 floats per 32x32
constexpr int kNSweep = 5;  // 4 sweeps -> absmax 0.0156 (marginal); 5 -> 0.0039. Keep 5.

// ws layout (floats):
//   P/log : [3][4096][1024]  (Q=0,K=1,V=2; overwritten in place by logs)
//   sumsq : [3][4096]        (||log||_F^2 per matrix)
//   attn  : [32][128][128]
// mean_log reuses the logQ region (dead after k_attn).
constexpr size_t OFF_SS   = (size_t)3 * kNMAT * kMSZ;
constexpr size_t OFF_ATTN = OFF_SS + (size_t)3 * kNMAT;

#define F4(p)  (*(float4*)(p))
#define CF4(p) (*(const float4*)(p))

// ---------------------------------------------------------------- bimap ----
// P_t = W_t^T X W_t for t in {Q,K,V}; one block per (b,m).
__global__ __launch_bounds__(256) void k_bimap(
    const float* __restrict__ x, const float* __restrict__ Wq,
    const float* __restrict__ Wk, const float* __restrict__ Wv,
    float* __restrict__ P) {
  __shared__ float Xs[64 * 68];   // X, row-major padded
  __shared__ float Wsh[64 * 32];  // current W, row-major
  __shared__ float Ts[64 * 36];   // T = X*W, padded
  const int t = threadIdx.x;
  const int bm = blockIdx.x;
  const float* xp = x + (size_t)bm * (kDIN * kDIN);
  {
    const int f0 = t * 16;
    const int r = f0 >> 6, c = f0 & 63;
    const float* src = xp + f0;
    float* dst = &Xs[r * 68 + c];
#pragma unroll
    for (int i = 0; i < 4; ++i) F4(dst + 4 * i) = CF4(src + 4 * i);
  }
  const int r0 = (t >> 3) * 2;   // stage-1 rows
  const int j0 = (t & 7) * 4;    // output cols
  const int i2 = t >> 3;         // stage-2 row
  for (int tt = 0; tt < 3; ++tt) {
    const float* W = (tt == 0) ? Wq : ((tt == 1) ? Wk : Wv);
    __syncthreads();  // protect Wsh/Ts from previous type (also covers Xs @ tt=0)
    F4(&Wsh[t * 8]) = CF4(W + t * 8);
    F4(&Wsh[t * 8 + 4]) = CF4(W + t * 8 + 4);
    __syncthreads();
    // stage 1: T = X * W   (64x32). X symmetric: X[r0][k] = Xs[k][r0] -> b64.
    float a0[4] = {0.f, 0.f, 0.f, 0.f}, a1[4] = {0.f, 0.f, 0.f, 0.f};
    for (int k = 0; k < 64; ++k) {
      const float2 x01 = *(const float2*)&Xs[k * 68 + r0];
      const float4 w = CF4(&Wsh[k * 32 + j0]);
      a0[0] += x01.x * w.x; a0[1] += x01.x * w.y; a0[2] += x01.x * w.z; a0[3] += x01.x * w.w;
      a1[0] += x01.y * w.x; a1[1] += x01.y * w.y; a1[2] += x01.y * w.z; a1[3] += x01.y * w.w;
    }
    F4(&Ts[r0 * 36 + j0])       = make_float4(a0[0], a0[1], a0[2], a0[3]);
    F4(&Ts[(r0 + 1) * 36 + j0]) = make_float4(a1[0], a1[1], a1[2], a1[3]);
    __syncthreads();
    // stage 2: P = W^T * T  (32x32)
    float b4[4] = {0.f, 0.f, 0.f, 0.f};
    for (int p = 0; p < 64; ++p) {
      const float wv = Wsh[p * 32 + i2];
      const float4 tv = CF4(&Ts[p * 36 + j0]);
      b4[0] += wv * tv.x; b4[1] += wv * tv.y; b4[2] += wv * tv.z; b4[3] += wv * tv.w;
    }
    F4(&P[((size_t)tt * kNMAT + bm) * kMSZ + i2 * 32 + j0]) =
        make_float4(b4[0], b4[1], b4[2], b4[3]);
  }
}

// ----------------------------------------------------- one-sided Jacobi ----
// Register-resident Brent-Luk one-sided Jacobi, TWO matrices per wave
// (mat = lane>>5), g = lane&15 (pair group), sub = (lane>>4)&1 (row half,
// 16 elems/lane as 8 float2).
// 6144 waves; LDS = ONE epilogue slot per wave (18.9 KB/block) -> 6 blocks/CU
// resident -> SINGLE dispatch pass, no tail.
// REGISTER BUDGET (R8+R10 lessons): any launch_bounds pressure below ~64
// VGPRs spills cp/cq to scratch (R8: (256,4)@4-mat -> 1.2 GB; R10: (256,6)
// @2-mat -> VGPR 40, 420 MB). (256,4) with the 2-mat layout gave VGPR=64,
// zero spill in R5 — use exactly that.
// Exchange uses the dead-`old` in-place DPP pattern (every updpp's old
// operand is a dead register, so the allocator ties dest in-place):
//   tv = is_g15 ? nq : cq;        // cq dead -> reuse its register
//   tv = updpp<shl1>(tv, np);     // g<=14: np[g+1], g15: nq
//   cp = is_g0 ? np : tv;
//   cq = updpp<shr1>(tv, nq);     // g>=1: nq[g-1], g0: tv(=np[1])
constexpr int kJSlot = 32 * 36 + 32;  // 1152 col data + 32 weights = 1184 floats
constexpr int kShl1 = 0x101, kShr1 = 0x111;

template <int CTRL>
__device__ __forceinline__ float updppf(float old_, float x) {
  return __builtin_bit_cast(float,
      __builtin_amdgcn_update_dpp(__builtin_bit_cast(int, old_),
                                  __builtin_bit_cast(int, x),
                                  CTRL, 0xf, 0xf, false));
}

__device__ __forceinline__ float xsign(float x, float s) {  // x * sgn(s)
  return __builtin_bit_cast(float,
      __builtin_bit_cast(int, x) ^
      (__builtin_bit_cast(int, s) & 0x80000000));
}

__global__ __launch_bounds__(256, 4) void k_jacobi_log(float* __restrict__ P,
                                                       float* __restrict__ sq) {
  __shared__ float lds[4 * kJSlot];  // ONE slot per wave, reused per matrix
  const int t = threadIdx.x;
  const int wid = t >> 6, lane = t & 63;
  const int mat = lane >> 5;         // which of the wave's 2 matrices
  const int g = lane & 15;           // pair group
  const int sub = (lane >> 4) & 1;   // row half
  const int off = sub * 16;

  const bool is_g0 = (g == 0);
  const bool is_g15 = (g == 15);
  // initial columns: g==0 -> {31, 0}; else {g, 31-g}
  const int p0 = is_g0 ? 31 : g;
  const int q0 = is_g0 ? 0 : 31 - g;

  const size_t gbase = (size_t)blockIdx.x * 8 + wid * 2;
  const float* A = P + (gbase + mat) * kMSZ;

  float2 cp2[8], cq2[8];
  {  // A is symmetric: column c == row c (row-major, 32 floats)
    const float* pr = A + p0 * 32 + off;
    const float* qr = A + q0 * 32 + off;
#pragma unroll
    for (int i = 0; i < 16; i += 4) {
      const float4 a = CF4(pr + i);
      cp2[i / 2]     = make_float2(a.x, a.y);
      cp2[i / 2 + 1] = make_float2(a.z, a.w);
      const float4 b = CF4(qr + i);
      cq2[i / 2]     = make_float2(b.x, b.y);
      cq2[i / 2 + 1] = make_float2(b.z, b.w);
    }
  }
  // initial squared norms (pairwise chains, then cross-sub reduce via xor16)
  float app, aqq;
  {
    float2 pa, qa;
    pa.x = cp2[0].x * cp2[0].x;  pa.y = cp2[0].y * cp2[0].y;
    qa.x = cq2[0].x * cq2[0].x;  qa.y = cq2[0].y * cq2[0].y;
#pragma unroll
    for (int j = 1; j < 8; ++j) {
      pa.x = fmaf(cp2[j].x, cp2[j].x, pa.x);
      pa.y = fmaf(cp2[j].y, cp2[j].y, pa.y);
      qa.x = fmaf(cq2[j].x, cq2[j].x, qa.x);
      qa.y = fmaf(cq2[j].y, cq2[j].y, qa.y);
    }
    app = pa.x + pa.y;
    aqq = qa.x + qa.y;
  }
  app += __shfl_xor(app, 16);
  aqq += __shfl_xor(aqq, 16);

  for (int sw = 0; sw < kNSweep; ++sw) {
    for (int r = 0; r < 31; ++r) {
      // apq = colp . colq (two float2 chains, then cross-sub reduce)
      float2 dA, dB;
      dA.x = cp2[0].x * cq2[0].x;  dA.y = cp2[0].y * cq2[0].y;
      dB.x = cp2[1].x * cq2[1].x;  dB.y = cp2[1].y * cq2[1].y;
#pragma unroll
      for (int j = 2; j < 8; j += 2) {
        dA.x = fmaf(cp2[j].x, cq2[j].x, dA.x);
        dA.y = fmaf(cp2[j].y, cq2[j].y, dA.y);
        dB.x = fmaf(cp2[j + 1].x, cq2[j + 1].x, dB.x);
        dB.y = fmaf(cp2[j + 1].y, cq2[j + 1].y, dB.y);
      }
      float apq = (dA.x + dA.y) + (dB.x + dB.y);
      apq += __shfl_xor(apq, 16);
      // rotation from (d, apq) with 3 transcendentals:
      //   h = sqrt(d^2 + 4 apq^2); t = sgn(d) * 2 apq / (|d| + h)
      //   c = rsq(1+t^2); s = t*c.   apq==0 -> t=0 -> exact identity.
      const float d = aqq - app;
      const float apq2 = 2.f * apq;
      float h2 = fmaf(d, d, apq2 * apq2);
      h2 = fmaxf(h2, 1e-38f);  // guard d=apq=0
      const float hr = __builtin_amdgcn_rsqf(h2);
      const float h = h2 * hr;
      const float den = fabsf(d) + h;
      const float t0 = apq2 * __builtin_amdgcn_rcpf(den);
      const float tt = xsign(t0, d);
      const float c = __builtin_amdgcn_rsqf(fmaf(tt, tt, 1.f));
      const float sn = tt * c;
      // fused rotate + in-place-dpp ring exchange, per component
#pragma unroll
      for (int j = 0; j < 8; ++j) {
        {
          const float cpc = cp2[j].x, cqc = cq2[j].x;
          const float np_ = fmaf(-sn, cqc, c * cpc);
          const float nq_ = fmaf(c, cqc, sn * cpc);
          float tv = is_g15 ? nq_ : cqc;
          tv = updppf<kShl1>(tv, np_);
          cp2[j].x = is_g0 ? np_ : tv;
          cq2[j].x = updppf<kShr1>(tv, nq_);
        }
        {
          const float cpc = cp2[j].y, cqc = cq2[j].y;
          const float np_ = fmaf(-sn, cqc, c * cpc);
          const float nq_ = fmaf(c, cqc, sn * cpc);
          float tv = is_g15 ? nq_ : cqc;
          tv = updppf<kShl1>(tv, np_);
          cp2[j].y = is_g0 ? np_ : tv;
          cq2[j].y = updppf<kShr1>(tv, nq_);
        }
      }
      // analytic norm update (rotation preserves app+aqq), flows with columns
      const float c2 = c * c, s2 = sn * sn, cs2 = 2.f * c * sn;
      const float capp = fmaf(c2, app, fmaf(s2, aqq, -cs2 * apq));
      const float caqq = (app + aqq) - capp;
      float tn = is_g15 ? caqq : app;  // app dead
      tn = updppf<kShl1>(tn, capp);
      app = is_g0 ? capp : tn;
      aqq = updppf<kShr1>(tn, caqq);
    }
  }
  // ---- epilogue ----
  // exact column norms in-register (this lane's half + partner's half)
  float ssp, ssq;
  {
    float2 pa, qa;
    pa.x = cp2[0].x * cp2[0].x;  pa.y = cp2[0].y * cp2[0].y;
    qa.x = cq2[0].x * cq2[0].x;  qa.y = cq2[0].y * cq2[0].y;
#pragma unroll
    for (int j = 1; j < 8; ++j) {
      pa.x = fmaf(cp2[j].x, cp2[j].x, pa.x);
      pa.y = fmaf(cp2[j].y, cp2[j].y, pa.y);
      qa.x = fmaf(cq2[j].x, cq2[j].x, qa.x);
      qa.y = fmaf(cq2[j].y, cq2[j].y, qa.y);
    }
    ssp = pa.x + pa.y;
    ssq = qa.x + qa.y;
  }
  ssp += __shfl_xor(ssp, 16);
  ssq += __shfl_xor(ssq, 16);
  const float lgp = 0.5f * logf(ssp);   // log sigma_p
  const float lgq = 0.5f * logf(ssq);
  const float wp = lgp * __builtin_amdgcn_rcpf(ssp);
  const float wq = lgq * __builtin_amdgcn_rcpf(ssq);
  {  // sumsq = sum over pairs (lgp^2 + lgq^2); reduce over g within 16-row
    float tot = fmaf(lgp, lgp, lgq * lgq);
    tot += __shfl_xor(tot, 1); tot += __shfl_xor(tot, 2);
    tot += __shfl_xor(tot, 4); tot += __shfl_xor(tot, 8);
    if ((lane & 31) == 0) sq[gbase + mat] = tot;
  }
  // sequential per-matrix epilogue: half-wave m dumps its columns+weights to
  // the wave's LDS slot, then the FULL wave computes log A = B diag(w) B^T.
  float* Bs = lds + wid * kJSlot;
  float* ncol = Bs + 1152;
  for (int m = 0; m < 2; ++m) {
    __builtin_amdgcn_wave_barrier();
    if (mat == m) {
#pragma unroll
      for (int i = 0; i < 16; i += 4) {
        F4(&Bs[p0 * 36 + off + i]) = make_float4(cp2[i/2].x, cp2[i/2].y,
                                                 cp2[i/2+1].x, cp2[i/2+1].y);
        F4(&Bs[q0 * 36 + off + i]) = make_float4(cq2[i/2].x, cq2[i/2].y,
                                                 cq2[i/2+1].x, cq2[i/2+1].y);
      }
      if (sub == 0) {
        ncol[p0] = wp;
        ncol[q0] = wq;
      }
    }
    __builtin_amdgcn_wave_barrier();
    {  // log A = B diag(w) B^T, 4x4 tile per lane, write back (row-major)
      float* Am = P + (gbase + m) * kMSZ;
      const int rr = (lane >> 3) * 4, cc = (lane & 7) * 4;
      float acc[4][4] = {};
      for (int c = 0; c < 32; ++c) {
        const float w = ncol[c];
        const float4 br = CF4(&Bs[c * 36 + rr]);
        const float4 bc = CF4(&Bs[c * 36 + cc]);
        const float wr[4]  = {w * br.x, w * br.y, w * br.z, w * br.w};
        const float bcv[4] = {bc.x, bc.y, bc.z, bc.w};
#pragma unroll
        for (int i = 0; i < 4; ++i)
#pragma unroll
          for (int j2 = 0; j2 < 4; ++j2) acc[i][j2] += wr[i] * bcv[j2];
      }
#pragma unroll
      for (int i = 0; i < 4; ++i)
        F4(&Am[(rr + i) * 32 + cc]) =
            make_float4(acc[i][0], acc[i][1], acc[i][2], acc[i][3]);
    }
    __builtin_amdgcn_wave_barrier();
  }
}

// ------------------------------------------------- scores/softmax/attn ----
// Block: (jt, b), 16-wide j tile -> 256 blocks (1/CU). K-chunk staged
// TRANSPOSED [k][i] so i-fragments are ds_read_b128; Q [k][j] -> b64.
__global__ __launch_bounds__(256) void k_attn(
    const float* __restrict__ P, const float* __restrict__ sq,
    float* __restrict__ attn) {
  __shared__ float Kt[32 * 132];   // [k][i], padded
  __shared__ float Qt[32 * 20];    // [k][j], padded
  __shared__ float Ss[128 * 20];   // scores [i][j]
  __shared__ float red[16 * 20];
  __shared__ float mcol[16];
  __shared__ float scol[16];
  const int t = threadIdx.x;
  const int b = blockIdx.y, jt = blockIdx.x;
  const int j0g = jt * 16;
  const float* logK = P + ((size_t)kNMAT + (size_t)b * kM) * kMSZ;
  const float* logQ = P + ((size_t)b * kM + j0g) * kMSZ;
  const int i0 = (t >> 3) * 4, j0 = (t & 7) * 2;
  float acc[4][2] = {};
  for (int dc = 0; dc < kMSZ; dc += 32) {
    __syncthreads();
    {  // stage Kt[k][i]: row r of logK, cols dc+c0..+15, transposed write
      const int r = t >> 1, c0 = (t & 1) * 16;
      const float* src = logK + (size_t)r * kMSZ + dc + c0;
#pragma unroll
      for (int ii = 0; ii < 16; ii += 4) {
        const float4 v = CF4(src + ii);
        Kt[(c0 + ii + 0) * 132 + r] = v.x;
        Kt[(c0 + ii + 1) * 132 + r] = v.y;
        Kt[(c0 + ii + 2) * 132 + r] = v.z;
        Kt[(c0 + ii + 3) * 132 + r] = v.w;
      }
    }
    {  // stage Qt[k][j]
      const int j = t >> 4, c0 = (t & 15) * 2;
      const float2 v = *(const float2*)(logQ + (size_t)j * kMSZ + dc + c0);
      Qt[(c0 + 0) * 20 + j] = v.x;
      Qt[(c0 + 1) * 20 + j] = v.y;
    }
    __syncthreads();
    for (int k = 0; k < 32; ++k) {
      const float4 kv = CF4(&Kt[k * 132 + i0]);
      const float2 qv = *(const float2*)&Qt[k * 20 + j0];
      acc[0][0] = fmaf(kv.x, qv.x, acc[0][0]);
      acc[0][1] = fmaf(kv.x, qv.y, acc[0][1]);
      acc[1][0] = fmaf(kv.y, qv.x, acc[1][0]);
      acc[1][1] = fmaf(kv.y, qv.y, acc[1][1]);
      acc[2][0] = fmaf(kv.z, qv.x, acc[2][0]);
      acc[2][1] = fmaf(kv.z, qv.y, acc[2][1]);
      acc[3][0] = fmaf(kv.w, qv.x, acc[3][0]);
      acc[3][1] = fmaf(kv.w, qv.y, acc[3][1]);
    }
  }
  {  // energy -> scores, into Ss[i][j]
    float k2v[4], q2v[2];
#pragma unroll
    for (int i = 0; i < 4; ++i) k2v[i] = sq[kNMAT + b * kM + i0 + i];
#pragma unroll
    for (int j2 = 0; j2 < 2; ++j2) q2v[j2] = sq[b * kM + j0g + j0 + j2];
#pragma unroll
    for (int i = 0; i < 4; ++i)
#pragma unroll
      for (int j2 = 0; j2 < 2; ++j2) {
        float e = k2v[i] + q2v[j2] - 2.f * acc[i][j2];
        e = fmaxf(e, 0.f);
        Ss[(i0 + i) * 20 + (j0 + j2)] = 1.f / (1.f + log1pf(e));
      }
  }
  __syncthreads();
  const int jl = t & 15, grp = t >> 4;  // 16 groups x 16 j-cols; group: 8 i-rows
  {
    float m = -1e30f;
#pragma unroll
    for (int i = 0; i < 8; ++i) m = fmaxf(m, Ss[(grp * 8 + i) * 20 + jl]);
    red[grp * 20 + jl] = m;
  }
  __syncthreads();
  if (t < 16) {
    float m = red[t];
#pragma unroll
    for (int g = 1; g < 16; ++g) m = fmaxf(m, red[g * 20 + t]);
    mcol[t] = m;
  }
  __syncthreads();
  {
    const float mj = mcol[jl];
    float s = 0.f;
#pragma unroll
    for (int i = 0; i < 8; ++i) s += expf(Ss[(grp * 8 + i) * 20 + jl] - mj);
    red[grp * 20 + jl] = s;
  }
  __syncthreads();
  if (t < 16) {
    float s = red[t];
#pragma unroll
    for (int g = 1; g < 16; ++g) s += red[g * 20 + t];
    scol[t] = 1.f / s;
  }
  __syncthreads();
  {  // write attn[b][j][i], coalesced in i
    const int il = t & 31, jg = t >> 5;
#pragma unroll
    for (int rep = 0; rep < 2; ++rep) {
      const int j2 = jg + rep * 8;
      const float mj = mcol[j2], is = scol[j2];
      float* dst = attn + ((size_t)b * kM + j0g + j2) * kM;
#pragma unroll
      for (int c4 = 0; c4 < 4; ++c4) {
        const int i = il + c4 * 32;
        dst[i] = expf(Ss[i * 20 + j2] - mj) * is;
      }
    }
  }
}

// -------------------------------------------------------------- meanlog ----
// ML[b][j][:] = sum_i attn[b][j][i] * logV[b][i][:]. Block: (jt, b), 16 j.
// All 16 j-accumulators in registers (thread owns 4 d-cols); attn weights
// broadcast from LDS (b128 per 4k); V streamed from global (L2-resident).
__global__ __launch_bounds__(256) void k_meanlog(
    const float* __restrict__ attn, const float* __restrict__ P,
    float* __restrict__ ML) {
  __shared__ float As[16 * 132];
  const int t = threadIdx.x;
  const int b = blockIdx.y, jt = blockIdx.x;
  const int j0g = jt * 16;
  const float* logV = P + ((size_t)2 * kNMAT + (size_t)b * kM) * kMSZ;
  {  // stage attn tile [16][128]
    const int j = t >> 4, k0 = (t & 15) * 8;
    const float* src = attn + ((size_t)b * kM + j0g + j) * kM + k0;
    F4(&As[j * 132 + k0])     = CF4(src);
    F4(&As[j * 132 + k0 + 4]) = CF4(src + 4);
  }
  __syncthreads();
  const int d0 = t * 4;
  float acc[16][4] = {};
  for (int k = 0; k < kM; k += 4) {
    float4 vr[4];
#pragma unroll
    for (int kk = 0; kk < 4; ++kk)
      vr[kk] = CF4(&logV[(size_t)(k + kk) * kMSZ + d0]);
#pragma unroll
    for (int j = 0; j < 16; ++j) {
      const float4 w = CF4(&As[j * 132 + k]);
      const float wv[4] = {w.x, w.y, w.z, w.w};
#pragma unroll
      for (int kk = 0; kk < 4; ++kk) {
        const float* vv = (const float*)&vr[kk];
#pragma unroll
        for (int dd = 0; dd < 4; ++dd)
          acc[j][dd] = fmaf(wv[kk], vv[dd], acc[j][dd]);
      }
    }
  }
#pragma unroll
  for (int j = 0; j < 16; ++j)
    F4(&ML[((size_t)b * kM + j0g + j) * kMSZ + d0]) =
        make_float4(acc[j][0], acc[j][1], acc[j][2], acc[j][3]);
}

// ------------------------------------------------------------------ exp ----
// out = exp(S): scaling-and-squaring + degree-7 Horner Taylor (||M||<=0.5
// after scaling -> truncation 1.6e-7, invisible vs the 0.0039 floor).
// 4 waves/block, one matrix per wave, private LDS slot, no s_barrier.
// M and T are SYMMETRIC, so row-fragments load as b128 from [k][r].
constexpr int kESlot = 2 * 1152;  // Mb + Tb

__global__ __launch_bounds__(256) void k_expm(const float* __restrict__ ML,
                                              float* __restrict__ out) {
  __shared__ float lds[4 * kESlot];
  const int t = threadIdx.x;
  const int wid = t >> 6, lane = t & 63;
  const size_t bm = (size_t)blockIdx.x * 4 + wid;
  float* Mb = lds + wid * kESlot;
  float* Tb = Mb + 1152;
  const float* S = ML + bm * kMSZ;
  const int r = lane >> 1, c0 = (lane & 1) * 16;
  float4 v0 = CF4(S + r * 32 + c0),     v1 = CF4(S + r * 32 + c0 + 4),
         v2 = CF4(S + r * 32 + c0 + 8), v3 = CF4(S + r * 32 + c0 + 12);
  float lsum = v0.x*v0.x + v0.y*v0.y + v0.z*v0.z + v0.w*v0.w
             + v1.x*v1.x + v1.y*v1.y + v1.z*v1.z + v1.w*v1.w
             + v2.x*v2.x + v2.y*v2.y + v2.z*v2.z + v2.w*v2.w
             + v3.x*v3.x + v3.y*v3.y + v3.z*v3.z + v3.w*v3.w;
#pragma unroll
  for (int d = 1; d < 64; d <<= 1) lsum += __shfl_xor(lsum, d);
  const float fn = sqrtf(lsum);     // Frobenius norm >= spectral norm
  int sc = 0;
  if (fn > 0.5f) sc = (int)ceilf(log2f(fn * 2.0f));
  const float scale = exp2f((float)(-sc));
  v0.x*=scale; v0.y*=scale; v0.z*=scale; v0.w*=scale;
  v1.x*=scale; v1.y*=scale; v1.z*=scale; v1.w*=scale;
  v2.x*=scale; v2.y*=scale; v2.z*=scale; v2.w*=scale;
  v3.x*=scale; v3.y*=scale; v3.z*=scale; v3.w*=scale;
  F4(&Mb[r * 36 + c0])      = v0;
  F4(&Mb[r * 36 + c0 + 4])  = v1;
  F4(&Mb[r * 36 + c0 + 8])  = v2;
  F4(&Mb[r * 36 + c0 + 12]) = v3;
  __builtin_amdgcn_wave_barrier();
  const int rr = (lane >> 3) * 4, cc = (lane & 7) * 4;
#pragma unroll
  for (int i = 0; i < 4; ++i) {  // T = I + M/7
    float4 v = F4(&Mb[(rr + i) * 36 + cc]);
    v.x = v.x * (1.f/7.f) + ((rr + i == cc + 0) ? 1.f : 0.f);
    v.y = v.y * (1.f/7.f) + ((rr + i == cc + 1) ? 1.f : 0.f);
    v.z = v.z * (1.f/7.f) + ((rr + i == cc + 2) ? 1.f : 0.f);
    v.w = v.w * (1.f/7.f) + ((rr + i == cc + 3) ? 1.f : 0.f);
    F4(&Tb[(rr + i) * 36 + cc]) = v;
  }
  __builtin_amdgcn_wave_barrier();
  for (int j = 6; j >= 1; --j) {  // T <- I + (M*T)/j, in place
    float a4[4][4] = {};
    for (int k = 0; k < 32; ++k) {
      const float4 mv = CF4(&Mb[k * 36 + rr]);  // M[rr..rr+3][k] by symmetry
      const float mvv[4] = {mv.x, mv.y, mv.z, mv.w};
      const float4 tv = CF4(&Tb[k * 36 + cc]);
      const float tvv[4] = {tv.x, tv.y, tv.z, tv.w};
#pragma unroll
      for (int i = 0; i < 4; ++i)
#pragma unroll
        for (int j2 = 0; j2 < 4; ++j2) a4[i][j2] += mvv[i] * tvv[j2];
    }
    const float inv = 1.f / (float)j;
#pragma unroll
    for (int i = 0; i < 4; ++i) {
      float4 v;
      v.x = a4[i][0] * inv + ((rr + i == cc + 0) ? 1.f : 0.f);
      v.y = a4[i][1] * inv + ((rr + i == cc + 1) ? 1.f : 0.f);
      v.z = a4[i][2] * inv + ((rr + i == cc + 2) ? 1.f : 0.f);
      v.w = a4[i][3] * inv + ((rr + i == cc + 3) ? 1.f : 0.f);
      F4(&Tb[(rr + i) * 36 + cc]) = v;
    }
    __builtin_amdgcn_wave_barrier();
  }
  for (int st = 0; st < sc; ++st) {  // T <- T*T, in place (T symmetric)
    float a4[4][4] = {};
    for (int k = 0; k < 32; ++k) {
      const float4 mv = CF4(&Tb[k * 36 + rr]);  // T[rr..rr+3][k] by symmetry
      const float mvv[4] = {mv.x, mv.y, mv.z, mv.w};
      const float4 tv = CF4(&Tb[k * 36 + cc]);
      const float tvv[4] = {tv.x, tv.y, tv.z, tv.w};
#pragma unroll
      for (int i = 0; i < 4; ++i)
#pragma unroll
        for (int j2 = 0; j2 < 4; ++j2) a4[i][j2] += mvv[i] * tvv[j2];
    }
#pragma unroll
    for (int i = 0; i < 4; ++i)
      F4(&Tb[(rr + i) * 36 + cc]) =
          make_float4(a4[i][0], a4[i][1], a4[i][2], a4[i][3]);
    __builtin_amdgcn_wave_barrier();
  }
#pragma unroll
  for (int i = 0; i < 4; ++i) {
    const float4 v = CF4(&Tb[(rr + i) * 36 + cc]);
    F4(&out[bm * kMSZ + (rr + i) * 32 + cc]) = v;
  }
}

// -------------------------------------------------------------- launch ----
extern "C" void kernel_launch(void* const* d_in, const int* in_sizes, int n_in,
                              void* d_out, int out_size, void* d_ws, size_t ws_size,
                              hipStream_t stream) {
  const float* x  = (const float*)d_in[0];
  const float* Wq = (const float*)d_in[1];
  const float* Wk = (const float*)d_in[2];
  const float* Wv = (const float*)d_in[3];
  float* ws   = (float*)d_ws;
  float* P    = ws;                 // [3][4096][1024]
  float* sq   = ws + OFF_SS;        // [3][4096]
  float* attn = ws + OFF_ATTN;      // [32][128][128]
  float* ML   = ws;                 // reuse logQ region (dead after k_attn)
  float* out  = (float*)d_out;

  k_bimap<<<kNMAT, 256, 0, stream>>>(x, Wq, Wk, Wv, P);
  k_jacobi_log<<<3 * kNMAT / 8, 256, 0, stream>>>(P, sq);
  k_attn<<<dim3(8, kBS), 256, 0, stream>>>(P, sq, attn);
  k_meanlog<<<dim3(8, kBS), 256, 0, stream>>>(attn, P, ML);
  k_expm<<<kNMAT / 4, 256, 0, stream>>>(ML, out);
}

// Round 12
// 458.511 us; speedup vs baseline: 1.2134x; 1.1476x over previous
//
#include <hip/hip_runtime.h>
#include <math.h>

// Problem constants
constexpr int kBS = 32, kM = 128, kNMAT = kBS * kM;         // 4096 (b,m) pairs
constexpr int kDIN = 64, kDOUT = 32, kMSZ = kDOUT * kDOUT;  // 1024 floats per 32x32
constexpr int kNSweep = 5;  // 4 sweeps -> absmax 0.0156 (marginal); 5 -> 0.0039. Keep 5.

// ws layout (floats):
//   P/log : [3][4096][1024]  (Q=0,K=1,V=2; overwritten in place by logs)
//   sumsq : [3][4096]        (||log||_F^2 per matrix)
//   attn  : [32][128][128]
// mean_log reuses the logQ region (dead after k_attn).
constexpr size_t OFF_SS   = (size_t)3 * kNMAT * kMSZ;
constexpr size_t OFF_ATTN = OFF_SS + (size_t)3 * kNMAT;

#define F4(p)  (*(float4*)(p))
#define CF4(p) (*(const float4*)(p))

// ---------------------------------------------------------------- bimap ----
// P_t = W_t^T X W_t for t in {Q,K,V}; one block per (b,m).
__global__ __launch_bounds__(256) void k_bimap(
    const float* __restrict__ x, const float* __restrict__ Wq,
    const float* __restrict__ Wk, const float* __restrict__ Wv,
    float* __restrict__ P) {
  __shared__ float Xs[64 * 68];   // X, row-major padded
  __shared__ float Wsh[64 * 32];  // current W, row-major
  __shared__ float Ts[64 * 36];   // T = X*W, padded
  const int t = threadIdx.x;
  const int bm = blockIdx.x;
  const float* xp = x + (size_t)bm * (kDIN * kDIN);
  {
    const int f0 = t * 16;
    const int r = f0 >> 6, c = f0 & 63;
    const float* src = xp + f0;
    float* dst = &Xs[r * 68 + c];
#pragma unroll
    for (int i = 0; i < 4; ++i) F4(dst + 4 * i) = CF4(src + 4 * i);
  }
  const int r0 = (t >> 3) * 2;   // stage-1 rows
  const int j0 = (t & 7) * 4;    // output cols
  const int i2 = t >> 3;         // stage-2 row
  for (int tt = 0; tt < 3; ++tt) {
    const float* W = (tt == 0) ? Wq : ((tt == 1) ? Wk : Wv);
    __syncthreads();  // protect Wsh/Ts from previous type (also covers Xs @ tt=0)
    F4(&Wsh[t * 8]) = CF4(W + t * 8);
    F4(&Wsh[t * 8 + 4]) = CF4(W + t * 8 + 4);
    __syncthreads();
    // stage 1: T = X * W   (64x32). X symmetric: X[r0][k] = Xs[k][r0] -> b64.
    float a0[4] = {0.f, 0.f, 0.f, 0.f}, a1[4] = {0.f, 0.f, 0.f, 0.f};
    for (int k = 0; k < 64; ++k) {
      const float2 x01 = *(const float2*)&Xs[k * 68 + r0];
      const float4 w = CF4(&Wsh[k * 32 + j0]);
      a0[0] += x01.x * w.x; a0[1] += x01.x * w.y; a0[2] += x01.x * w.z; a0[3] += x01.x * w.w;
      a1[0] += x01.y * w.x; a1[1] += x01.y * w.y; a1[2] += x01.y * w.z; a1[3] += x01.y * w.w;
    }
    F4(&Ts[r0 * 36 + j0])       = make_float4(a0[0], a0[1], a0[2], a0[3]);
    F4(&Ts[(r0 + 1) * 36 + j0]) = make_float4(a1[0], a1[1], a1[2], a1[3]);
    __syncthreads();
    // stage 2: P = W^T * T  (32x32)
    float b4[4] = {0.f, 0.f, 0.f, 0.f};
    for (int p = 0; p < 64; ++p) {
      const float wv = Wsh[p * 32 + i2];
      const float4 tv = CF4(&Ts[p * 36 + j0]);
      b4[0] += wv * tv.x; b4[1] += wv * tv.y; b4[2] += wv * tv.z; b4[3] += wv * tv.w;
    }
    F4(&P[((size_t)tt * kNMAT + bm) * kMSZ + i2 * 32 + j0]) =
        make_float4(b4[0], b4[1], b4[2], b4[3]);
  }
}

// ----------------------------------------------------- one-sided Jacobi ----
// Register-resident Brent-Luk one-sided Jacobi, TWO matrices per wave
// (mat = lane>>5), g = lane&15 (pair group), sub = (lane>>4)&1 (row half,
// 16 scalar elems/lane). This round loop is R5's VERBATIM (291 us, VGPR 64,
// zero spill) — every variant tried (4-mat/wave, float2 packing, in-place
// DPP with extra select, tighter launch bounds) regressed it.
// Changes vs R5 are epilogue-only: single LDS slot per wave (18.9 KB/block,
// was 37.9) reused sequentially for the wave's 2 matrices, and in-register
// column norms (no LDS norm pass).
// REGISTER BUDGET (R8+R10): below ~64 VGPRs the column arrays spill to
// scratch (GB-scale HBM traffic). (256,4) + this layout = 64 VGPR, no spill.
constexpr int kJSlot = 32 * 36 + 32;  // 1152 col data + 32 weights = 1184 floats
constexpr int kShl1 = 0x101, kShr1 = 0x111;

template <int CTRL>
__device__ __forceinline__ float updppf(float old_, float x) {
  return __builtin_bit_cast(float,
      __builtin_amdgcn_update_dpp(__builtin_bit_cast(int, old_),
                                  __builtin_bit_cast(int, x),
                                  CTRL, 0xf, 0xf, false));
}

__device__ __forceinline__ float xsign(float x, float s) {  // x * sgn(s)
  return __builtin_bit_cast(float,
      __builtin_bit_cast(int, x) ^
      (__builtin_bit_cast(int, s) & 0x80000000));
}

__global__ __launch_bounds__(256, 4) void k_jacobi_log(float* __restrict__ P,
                                                       float* __restrict__ sq) {
  __shared__ float lds[4 * kJSlot];  // ONE slot per wave, reused per matrix
  const int t = threadIdx.x;
  const int wid = t >> 6, lane = t & 63;
  const int mat = lane >> 5;         // which of the wave's 2 matrices
  const int g = lane & 15;           // pair group
  const int sub = (lane >> 4) & 1;   // row half
  const int off = sub * 16;

  const bool is_g0 = (g == 0);
  // initial columns: g==0 -> {31, 0}; else {g, 31-g}
  const int p0 = is_g0 ? 31 : g;
  const int q0 = is_g0 ? 0 : 31 - g;

  const size_t gbase = (size_t)blockIdx.x * 8 + wid * 2;
  const float* A = P + (gbase + mat) * kMSZ;

  float cp[16], cq[16];
  {  // A is symmetric: column c == row c (row-major, 32 floats)
    const float* pr = A + p0 * 32 + off;
    const float* qr = A + q0 * 32 + off;
#pragma unroll
    for (int i = 0; i < 16; i += 4) {
      const float4 a = CF4(pr + i);
      cp[i] = a.x; cp[i + 1] = a.y; cp[i + 2] = a.z; cp[i + 3] = a.w;
      const float4 b = CF4(qr + i);
      cq[i] = b.x; cq[i + 1] = b.y; cq[i + 2] = b.z; cq[i + 3] = b.w;
    }
  }
  // initial squared norms (reduce across the 2 subs: lanes l, l^16)
  float app = 0.f, aqq = 0.f;
#pragma unroll
  for (int i = 0; i < 16; ++i) {
    app = fmaf(cp[i], cp[i], app);
    aqq = fmaf(cq[i], cq[i], aqq);
  }
  app += __shfl_xor(app, 16);
  aqq += __shfl_xor(aqq, 16);

  for (int sw = 0; sw < kNSweep; ++sw) {
    for (int r = 0; r < 31; ++r) {
      // apq = colp . colq (two FMA chains for ILP, then cross-sub reduce)
      float d0 = cp[0] * cq[0], d1 = cp[1] * cq[1];
#pragma unroll
      for (int i = 2; i < 16; i += 2) {
        d0 = fmaf(cp[i], cq[i], d0);
        d1 = fmaf(cp[i + 1], cq[i + 1], d1);
      }
      float apq = d0 + d1;
      apq += __shfl_xor(apq, 16);
      // rotation from (d, apq) with 3 transcendentals (validated R9/R11):
      //   h = sqrt(d^2 + 4 apq^2); t = sgn(d) * 2 apq / (|d| + h)
      //   c = rsq(1+t^2); s = t*c.   apq==0 -> t=0 -> exact identity.
      const float d = aqq - app;
      const float apq2 = 2.f * apq;
      float h2 = fmaf(d, d, apq2 * apq2);
      h2 = fmaxf(h2, 1e-38f);  // guard d=apq=0
      const float hr = __builtin_amdgcn_rsqf(h2);
      const float h = h2 * hr;
      const float den = fabsf(d) + h;
      const float t0 = apq2 * __builtin_amdgcn_rcpf(den);
      const float tt = xsign(t0, d);
      const float c = __builtin_amdgcn_rsqf(fmaf(tt, tt, 1.f));
      const float sn = tt * c;
      float np[16], nq[16];
#pragma unroll
      for (int i = 0; i < 16; ++i) {
        const float t1 = c * cp[i];
        const float t2 = sn * cp[i];
        np[i] = fmaf(-sn, cq[i], t1);
        nq[i] = fmaf(c, cq[i], t2);
      }
      // analytic norm update (rotation preserves app+aqq; np.nq == 0)
      const float c2 = c * c, s2 = sn * sn, cs2 = 2.f * c * sn;
      const float capp = fmaf(c2, app, fmaf(s2, aqq, -cs2 * apq));
      const float caqq = (app + aqq) - capp;
      // ring exchange (R5 pattern)
#pragma unroll
      for (int i = 0; i < 16; ++i) {
        const float cpm = updppf<kShl1>(nq[i], np[i]);
        cp[i] = is_g0 ? np[i] : cpm;
        cq[i] = updppf<kShr1>(cpm, nq[i]);
      }
      {
        const float capm = updppf<kShl1>(caqq, capp);
        app = is_g0 ? capp : capm;
        aqq = updppf<kShr1>(capm, caqq);
      }
    }
  }
  // ---- epilogue ----
  // exact column norms in-register (this lane's half + partner's half)
  float ssp = 0.f, ssq = 0.f;
#pragma unroll
  for (int i = 0; i < 16; ++i) {
    ssp = fmaf(cp[i], cp[i], ssp);
    ssq = fmaf(cq[i], cq[i], ssq);
  }
  ssp += __shfl_xor(ssp, 16);
  ssq += __shfl_xor(ssq, 16);
  const float lgp = 0.5f * logf(ssp);   // log sigma_p
  const float lgq = 0.5f * logf(ssq);
  const float wp = lgp * __builtin_amdgcn_rcpf(ssp);
  const float wq = lgq * __builtin_amdgcn_rcpf(ssq);
  {  // sumsq = sum over pairs (lgp^2 + lgq^2); reduce over g within 16-row
    float tot = fmaf(lgp, lgp, lgq * lgq);
    tot += __shfl_xor(tot, 1); tot += __shfl_xor(tot, 2);
    tot += __shfl_xor(tot, 4); tot += __shfl_xor(tot, 8);
    if ((lane & 31) == 0) sq[gbase + mat] = tot;
  }
  // sequential per-matrix epilogue: half-wave m dumps its columns+weights to
  // the wave's LDS slot, then the FULL wave computes log A = B diag(w) B^T.
  float* Bs = lds + wid * kJSlot;
  float* ncol = Bs + 1152;
  for (int m = 0; m < 2; ++m) {
    __builtin_amdgcn_wave_barrier();
    if (mat == m) {
#pragma unroll
      for (int i = 0; i < 16; i += 4) {
        F4(&Bs[p0 * 36 + off + i]) = make_float4(cp[i], cp[i+1], cp[i+2], cp[i+3]);
        F4(&Bs[q0 * 36 + off + i]) = make_float4(cq[i], cq[i+1], cq[i+2], cq[i+3]);
      }
      if (sub == 0) {
        ncol[p0] = wp;
        ncol[q0] = wq;
      }
    }
    __builtin_amdgcn_wave_barrier();
    {  // log A = B diag(w) B^T, 4x4 tile per lane, write back (row-major)
      float* Am = P + (gbase + m) * kMSZ;
      const int rr = (lane >> 3) * 4, cc = (lane & 7) * 4;
      float acc[4][4] = {};
      for (int c = 0; c < 32; ++c) {
        const float w = ncol[c];
        const float4 br = CF4(&Bs[c * 36 + rr]);
        const float4 bc = CF4(&Bs[c * 36 + cc]);
        const float wr[4]  = {w * br.x, w * br.y, w * br.z, w * br.w};
        const float bcv[4] = {bc.x, bc.y, bc.z, bc.w};
#pragma unroll
        for (int i = 0; i < 4; ++i)
#pragma unroll
          for (int j2 = 0; j2 < 4; ++j2) acc[i][j2] += wr[i] * bcv[j2];
      }
#pragma unroll
      for (int i = 0; i < 4; ++i)
        F4(&Am[(rr + i) * 32 + cc]) =
            make_float4(acc[i][0], acc[i][1], acc[i][2], acc[i][3]);
    }
    __builtin_amdgcn_wave_barrier();
  }
}

// ------------------------------------------------- scores/softmax/attn ----
// Block: (jt, b), 16-wide j tile -> 256 blocks (1/CU). K-chunk staged
// TRANSPOSED [k][i] so i-fragments are ds_read_b128; Q [k][j] -> b64.
__global__ __launch_bounds__(256) void k_attn(
    const float* __restrict__ P, const float* __restrict__ sq,
    float* __restrict__ attn) {
  __shared__ float Kt[32 * 132];   // [k][i], padded
  __shared__ float Qt[32 * 20];    // [k][j], padded
  __shared__ float Ss[128 * 20];   // scores [i][j]
  __shared__ float red[16 * 20];
  __shared__ float mcol[16];
  __shared__ float scol[16];
  const int t = threadIdx.x;
  const int b = blockIdx.y, jt = blockIdx.x;
  const int j0g = jt * 16;
  const float* logK = P + ((size_t)kNMAT + (size_t)b * kM) * kMSZ;
  const float* logQ = P + ((size_t)b * kM + j0g) * kMSZ;
  const int i0 = (t >> 3) * 4, j0 = (t & 7) * 2;
  float acc[4][2] = {};
  for (int dc = 0; dc < kMSZ; dc += 32) {
    __syncthreads();
    {  // stage Kt[k][i]: row r of logK, cols dc+c0..+15, transposed write
      const int r = t >> 1, c0 = (t & 1) * 16;
      const float* src = logK + (size_t)r * kMSZ + dc + c0;
#pragma unroll
      for (int ii = 0; ii < 16; ii += 4) {
        const float4 v = CF4(src + ii);
        Kt[(c0 + ii + 0) * 132 + r] = v.x;
        Kt[(c0 + ii + 1) * 132 + r] = v.y;
        Kt[(c0 + ii + 2) * 132 + r] = v.z;
        Kt[(c0 + ii + 3) * 132 + r] = v.w;
      }
    }
    {  // stage Qt[k][j]
      const int j = t >> 4, c0 = (t & 15) * 2;
      const float2 v = *(const float2*)(logQ + (size_t)j * kMSZ + dc + c0);
      Qt[(c0 + 0) * 20 + j] = v.x;
      Qt[(c0 + 1) * 20 + j] = v.y;
    }
    __syncthreads();
    for (int k = 0; k < 32; ++k) {
      const float4 kv = CF4(&Kt[k * 132 + i0]);
      const float2 qv = *(const float2*)&Qt[k * 20 + j0];
      acc[0][0] = fmaf(kv.x, qv.x, acc[0][0]);
      acc[0][1] = fmaf(kv.x, qv.y, acc[0][1]);
      acc[1][0] = fmaf(kv.y, qv.x, acc[1][0]);
      acc[1][1] = fmaf(kv.y, qv.y, acc[1][1]);
      acc[2][0] = fmaf(kv.z, qv.x, acc[2][0]);
      acc[2][1] = fmaf(kv.z, qv.y, acc[2][1]);
      acc[3][0] = fmaf(kv.w, qv.x, acc[3][0]);
      acc[3][1] = fmaf(kv.w, qv.y, acc[3][1]);
    }
  }
  {  // energy -> scores, into Ss[i][j]
    float k2v[4], q2v[2];
#pragma unroll
    for (int i = 0; i < 4; ++i) k2v[i] = sq[kNMAT + b * kM + i0 + i];
#pragma unroll
    for (int j2 = 0; j2 < 2; ++j2) q2v[j2] = sq[b * kM + j0g + j0 + j2];
#pragma unroll
    for (int i = 0; i < 4; ++i)
#pragma unroll
      for (int j2 = 0; j2 < 2; ++j2) {
        float e = k2v[i] + q2v[j2] - 2.f * acc[i][j2];
        e = fmaxf(e, 0.f);
        Ss[(i0 + i) * 20 + (j0 + j2)] = 1.f / (1.f + log1pf(e));
      }
  }
  __syncthreads();
  const int jl = t & 15, grp = t >> 4;  // 16 groups x 16 j-cols; group: 8 i-rows
  {
    float m = -1e30f;
#pragma unroll
    for (int i = 0; i < 8; ++i) m = fmaxf(m, Ss[(grp * 8 + i) * 20 + jl]);
    red[grp * 20 + jl] = m;
  }
  __syncthreads();
  if (t < 16) {
    float m = red[t];
#pragma unroll
    for (int g = 1; g < 16; ++g) m = fmaxf(m, red[g * 20 + t]);
    mcol[t] = m;
  }
  __syncthreads();
  {
    const float mj = mcol[jl];
    float s = 0.f;
#pragma unroll
    for (int i = 0; i < 8; ++i) s += expf(Ss[(grp * 8 + i) * 20 + jl] - mj);
    red[grp * 20 + jl] = s;
  }
  __syncthreads();
  if (t < 16) {
    float s = red[t];
#pragma unroll
    for (int g = 1; g < 16; ++g) s += red[g * 20 + t];
    scol[t] = 1.f / s;
  }
  __syncthreads();
  {  // write attn[b][j][i], coalesced in i
    const int il = t & 31, jg = t >> 5;
#pragma unroll
    for (int rep = 0; rep < 2; ++rep) {
      const int j2 = jg + rep * 8;
      const float mj = mcol[j2], is = scol[j2];
      float* dst = attn + ((size_t)b * kM + j0g + j2) * kM;
#pragma unroll
      for (int c4 = 0; c4 < 4; ++c4) {
        const int i = il + c4 * 32;
        dst[i] = expf(Ss[i * 20 + j2] - mj) * is;
      }
    }
  }
}

// -------------------------------------------------------------- meanlog ----
// ML[b][j][:] = sum_i attn[b][j][i] * logV[b][i][:]. Block: (jt, b), 16 j.
// All 16 j-accumulators in registers (thread owns 4 d-cols); attn weights
// broadcast from LDS (b128 per 4k); V streamed from global (L2-resident).
__global__ __launch_bounds__(256) void k_meanlog(
    const float* __restrict__ attn, const float* __restrict__ P,
    float* __restrict__ ML) {
  __shared__ float As[16 * 132];
  const int t = threadIdx.x;
  const int b = blockIdx.y, jt = blockIdx.x;
  const int j0g = jt * 16;
  const float* logV = P + ((size_t)2 * kNMAT + (size_t)b * kM) * kMSZ;
  {  // stage attn tile [16][128]
    const int j = t >> 4, k0 = (t & 15) * 8;
    const float* src = attn + ((size_t)b * kM + j0g + j) * kM + k0;
    F4(&As[j * 132 + k0])     = CF4(src);
    F4(&As[j * 132 + k0 + 4]) = CF4(src + 4);
  }
  __syncthreads();
  const int d0 = t * 4;
  float acc[16][4] = {};
  for (int k = 0; k < kM; k += 4) {
    float4 vr[4];
#pragma unroll
    for (int kk = 0; kk < 4; ++kk)
      vr[kk] = CF4(&logV[(size_t)(k + kk) * kMSZ + d0]);
#pragma unroll
    for (int j = 0; j < 16; ++j) {
      const float4 w = CF4(&As[j * 132 + k]);
      const float wv[4] = {w.x, w.y, w.z, w.w};
#pragma unroll
      for (int kk = 0; kk < 4; ++kk) {
        const float* vv = (const float*)&vr[kk];
#pragma unroll
        for (int dd = 0; dd < 4; ++dd)
          acc[j][dd] = fmaf(wv[kk], vv[dd], acc[j][dd]);
      }
    }
  }
#pragma unroll
  for (int j = 0; j < 16; ++j)
    F4(&ML[((size_t)b * kM + j0g + j) * kMSZ + d0]) =
        make_float4(acc[j][0], acc[j][1], acc[j][2], acc[j][3]);
}

// ------------------------------------------------------------------ exp ----
// out = exp(S): scaling-and-squaring + degree-7 Horner Taylor (||M||<=0.5
// after scaling -> truncation 1.6e-7, invisible vs the 0.0039 floor).
// 4 waves/block, one matrix per wave, private LDS slot, no s_barrier.
// M and T are SYMMETRIC, so row-fragments load as b128 from [k][r].
constexpr int kESlot = 2 * 1152;  // Mb + Tb

__global__ __launch_bounds__(256) void k_expm(const float* __restrict__ ML,
                                              float* __restrict__ out) {
  __shared__ float lds[4 * kESlot];
  const int t = threadIdx.x;
  const int wid = t >> 6, lane = t & 63;
  const size_t bm = (size_t)blockIdx.x * 4 + wid;
  float* Mb = lds + wid * kESlot;
  float* Tb = Mb + 1152;
  const float* S = ML + bm * kMSZ;
  const int r = lane >> 1, c0 = (lane & 1) * 16;
  float4 v0 = CF4(S + r * 32 + c0),     v1 = CF4(S + r * 32 + c0 + 4),
         v2 = CF4(S + r * 32 + c0 + 8), v3 = CF4(S + r * 32 + c0 + 12);
  float lsum = v0.x*v0.x + v0.y*v0.y + v0.z*v0.z + v0.w*v0.w
             + v1.x*v1.x + v1.y*v1.y + v1.z*v1.z + v1.w*v1.w
             + v2.x*v2.x + v2.y*v2.y + v2.z*v2.z + v2.w*v2.w
             + v3.x*v3.x + v3.y*v3.y + v3.z*v3.z + v3.w*v3.w;
#pragma unroll
  for (int d = 1; d < 64; d <<= 1) lsum += __shfl_xor(lsum, d);
  const float fn = sqrtf(lsum);     // Frobenius norm >= spectral norm
  int sc = 0;
  if (fn > 0.5f) sc = (int)ceilf(log2f(fn * 2.0f));
  const float scale = exp2f((float)(-sc));
  v0.x*=scale; v0.y*=scale; v0.z*=scale; v0.w*=scale;
  v1.x*=scale; v1.y*=scale; v1.z*=scale; v1.w*=scale;
  v2.x*=scale; v2.y*=scale; v2.z*=scale; v2.w*=scale;
  v3.x*=scale; v3.y*=scale; v3.z*=scale; v3.w*=scale;
  F4(&Mb[r * 36 + c0])      = v0;
  F4(&Mb[r * 36 + c0 + 4])  = v1;
  F4(&Mb[r * 36 + c0 + 8])  = v2;
  F4(&Mb[r * 36 + c0 + 12]) = v3;
  __builtin_amdgcn_wave_barrier();
  const int rr = (lane >> 3) * 4, cc = (lane & 7) * 4;
#pragma unroll
  for (int i = 0; i < 4; ++i) {  // T = I + M/7
    float4 v = F4(&Mb[(rr + i) * 36 + cc]);
    v.x = v.x * (1.f/7.f) + ((rr + i == cc + 0) ? 1.f : 0.f);
    v.y = v.y * (1.f/7.f) + ((rr + i == cc + 1) ? 1.f : 0.f);
    v.z = v.z * (1.f/7.f) + ((rr + i == cc + 2) ? 1.f : 0.f);
    v.w = v.w * (1.f/7.f) + ((rr + i == cc + 3) ? 1.f : 0.f);
    F4(&Tb[(rr + i) * 36 + cc]) = v;
  }
  __builtin_amdgcn_wave_barrier();
  for (int j = 6; j >= 1; --j) {  // T <- I + (M*T)/j, in place
    float a4[4][4] = {};
    for (int k = 0; k < 32; ++k) {
      const float4 mv = CF4(&Mb[k * 36 + rr]);  // M[rr..rr+3][k] by symmetry
      const float mvv[4] = {mv.x, mv.y, mv.z, mv.w};
      const float4 tv = CF4(&Tb[k * 36 + cc]);
      const float tvv[4] = {tv.x, tv.y, tv.z, tv.w};
#pragma unroll
      for (int i = 0; i < 4; ++i)
#pragma unroll
        for (int j2 = 0; j2 < 4; ++j2) a4[i][j2] += mvv[i] * tvv[j2];
    }
    const float inv = 1.f / (float)j;
#pragma unroll
    for (int i = 0; i < 4; ++i) {
      float4 v;
      v.x = a4[i][0] * inv + ((rr + i == cc + 0) ? 1.f : 0.f);
      v.y = a4[i][1] * inv + ((rr + i == cc + 1) ? 1.f : 0.f);
      v.z = a4[i][2] * inv + ((rr + i == cc + 2) ? 1.f : 0.f);
      v.w = a4[i][3] * inv + ((rr + i == cc + 3) ? 1.f : 0.f);
      F4(&Tb[(rr + i) * 36 + cc]) = v;
    }
    __builtin_amdgcn_wave_barrier();
  }
  for (int st = 0; st < sc; ++st) {  // T <- T*T, in place (T symmetric)
    float a4[4][4] = {};
    for (int k = 0; k < 32; ++k) {
      const float4 mv = CF4(&Tb[k * 36 + rr]);  // T[rr..rr+3][k] by symmetry
      const float mvv[4] = {mv.x, mv.y, mv.z, mv.w};
      const float4 tv = CF4(&Tb[k * 36 + cc]);
      const float tvv[4] = {tv.x, tv.y, tv.z, tv.w};
#pragma unroll
      for (int i = 0; i < 4; ++i)
#pragma unroll
        for (int j2 = 0; j2 < 4; ++j2) a4[i][j2] += mvv[i] * tvv[j2];
    }
#pragma unroll
    for (int i = 0; i < 4; ++i)
      F4(&Tb[(rr + i) * 36 + cc]) =
          make_float4(a4[i][0], a4[i][1], a4[i][2], a4[i][3]);
    __builtin_amdgcn_wave_barrier();
  }
#pragma unroll
  for (int i = 0; i < 4; ++i) {
    const float4 v = CF4(&Tb[(rr + i) * 36 + cc]);
    F4(&out[bm * kMSZ + (rr + i) * 32 + cc]) = v;
  }
}

// -------------------------------------------------------------- launch ----
extern "C" void kernel_launch(void* const* d_in, const int* in_sizes, int n_in,
                              void* d_out, int out_size, void* d_ws, size_t ws_size,
                              hipStream_t stream) {
  const float* x  = (const float*)d_in[0];
  const float* Wq = (const float*)d_in[1];
  const float* Wk = (const float*)d_in[2];
  const float* Wv = (const float*)d_in[3];
  float* ws   = (float*)d_ws;
  float* P    = ws;                 // [3][4096][1024]
  float* sq   = ws + OFF_SS;        // [3][4096]
  float* attn = ws + OFF_ATTN;      // [32][128][128]
  float* ML   = ws;                 // reuse logQ region (dead after k_attn)
  float* out  = (float*)d_out;

  k_bimap<<<kNMAT, 256, 0, stream>>>(x, Wq, Wk, Wv, P);
  k_jacobi_log<<<3 * kNMAT / 8, 256, 0, stream>>>(P, sq);
  k_attn<<<dim3(8, kBS), 256, 0, stream>>>(P, sq, attn);
  k_meanlog<<<dim3(8, kBS), 256, 0, stream>>>(attn, P, ML);
  k_expm<<<kNMAT / 4, 256, 0, stream>>>(ML, out);
}

// Round 13
// 452.886 us; speedup vs baseline: 1.2285x; 1.0124x over previous
//
#include <hip/hip_runtime.h>
#include <math.h>

// Problem constants
constexpr int kBS = 32, kM = 128, kNMAT = kBS * kM;         // 4096 (b,m) pairs
constexpr int kDIN = 64, kDOUT = 32, kMSZ = kDOUT * kDOUT;  // 1024 floats per 32x32
constexpr int kNSweep = 5;  // 4 sweeps -> absmax 0.0156 (marginal); 5 -> 0.0039. Keep 5.

// ws layout (floats):
//   P/log : [3][4096][1024]  (Q=0,K=1,V=2; overwritten in place by logs)
//   sumsq : [3][4096]        (||log||_F^2 per matrix)
//   attn  : [32][128][128]
// mean_log reuses the logQ region (dead after k_attn).
constexpr size_t OFF_SS   = (size_t)3 * kNMAT * kMSZ;
constexpr size_t OFF_ATTN = OFF_SS + (size_t)3 * kNMAT;

#define F4(p)  (*(float4*)(p))
#define CF4(p) (*(const float4*)(p))

// ---------------------------------------------------------------- bimap ----
// P_t = W_t^T X W_t for t in {Q,K,V}; one block per (b,m).
__global__ __launch_bounds__(256) void k_bimap(
    const float* __restrict__ x, const float* __restrict__ Wq,
    const float* __restrict__ Wk, const float* __restrict__ Wv,
    float* __restrict__ P) {
  __shared__ float Xs[64 * 68];   // X, row-major padded
  __shared__ float Wsh[64 * 32];  // current W, row-major
  __shared__ float Ts[64 * 36];   // T = X*W, padded
  const int t = threadIdx.x;
  const int bm = blockIdx.x;
  const float* xp = x + (size_t)bm * (kDIN * kDIN);
  {
    const int f0 = t * 16;
    const int r = f0 >> 6, c = f0 & 63;
    const float* src = xp + f0;
    float* dst = &Xs[r * 68 + c];
#pragma unroll
    for (int i = 0; i < 4; ++i) F4(dst + 4 * i) = CF4(src + 4 * i);
  }
  const int r0 = (t >> 3) * 2;   // stage-1 rows
  const int j0 = (t & 7) * 4;    // output cols
  const int i2 = t >> 3;         // stage-2 row
  for (int tt = 0; tt < 3; ++tt) {
    const float* W = (tt == 0) ? Wq : ((tt == 1) ? Wk : Wv);
    __syncthreads();  // protect Wsh/Ts from previous type (also covers Xs @ tt=0)
    F4(&Wsh[t * 8]) = CF4(W + t * 8);
    F4(&Wsh[t * 8 + 4]) = CF4(W + t * 8 + 4);
    __syncthreads();
    // stage 1: T = X * W   (64x32). X symmetric: X[r0][k] = Xs[k][r0] -> b64.
    float a0[4] = {0.f, 0.f, 0.f, 0.f}, a1[4] = {0.f, 0.f, 0.f, 0.f};
    for (int k = 0; k < 64; ++k) {
      const float2 x01 = *(const float2*)&Xs[k * 68 + r0];
      const float4 w = CF4(&Wsh[k * 32 + j0]);
      a0[0] += x01.x * w.x; a0[1] += x01.x * w.y; a0[2] += x01.x * w.z; a0[3] += x01.x * w.w;
      a1[0] += x01.y * w.x; a1[1] += x01.y * w.y; a1[2] += x01.y * w.z; a1[3] += x01.y * w.w;
    }
    F4(&Ts[r0 * 36 + j0])       = make_float4(a0[0], a0[1], a0[2], a0[3]);
    F4(&Ts[(r0 + 1) * 36 + j0]) = make_float4(a1[0], a1[1], a1[2], a1[3]);
    __syncthreads();
    // stage 2: P = W^T * T  (32x32)
    float b4[4] = {0.f, 0.f, 0.f, 0.f};
    for (int p = 0; p < 64; ++p) {
      const float wv = Wsh[p * 32 + i2];
      const float4 tv = CF4(&Ts[p * 36 + j0]);
      b4[0] += wv * tv.x; b4[1] += wv * tv.y; b4[2] += wv * tv.z; b4[3] += wv * tv.w;
    }
    F4(&P[((size_t)tt * kNMAT + bm) * kMSZ + i2 * 32 + j0]) =
        make_float4(b4[0], b4[1], b4[2], b4[3]);
  }
}

// ----------------------------------------------------- one-sided Jacobi ----
// Register-resident Brent-Luk one-sided Jacobi, TWO matrices per wave
// (mat = lane>>5), g = lane&15 (pair group), sub = (lane>>4)&1 (row half,
// 16 scalar elems/lane). Round-loop semantics are R5's VERBATIM (291 us,
// zero spill) with ONE codegen change: rotate+exchange fused per element
// (np_/nq_/cpm are loop-local scalars, not [16] arrays) — same instruction
// sequence, ~16 fewer live VGPRs, kills the R12 scratch traffic (WRITE 128
// vs 49 MB) from the arrays spilling.
// REGISTER BUDGET (R8+R10): below ~64 VGPRs the column arrays spill to
// scratch (GB-scale HBM traffic) IF launch bounds force it; (256,4) leaves
// budget 128 and the compiler lands where it likes.
constexpr int kJSlot = 32 * 36 + 32;  // 1152 col data + 32 weights = 1184 floats
constexpr int kShl1 = 0x101, kShr1 = 0x111;

template <int CTRL>
__device__ __forceinline__ float updppf(float old_, float x) {
  return __builtin_bit_cast(float,
      __builtin_amdgcn_update_dpp(__builtin_bit_cast(int, old_),
                                  __builtin_bit_cast(int, x),
                                  CTRL, 0xf, 0xf, false));
}

__device__ __forceinline__ float xsign(float x, float s) {  // x * sgn(s)
  return __builtin_bit_cast(float,
      __builtin_bit_cast(int, x) ^
      (__builtin_bit_cast(int, s) & 0x80000000));
}

__global__ __launch_bounds__(256, 4) void k_jacobi_log(float* __restrict__ P,
                                                       float* __restrict__ sq) {
  __shared__ float lds[4 * kJSlot];  // ONE slot per wave, reused per matrix
  const int t = threadIdx.x;
  const int wid = t >> 6, lane = t & 63;
  const int mat = lane >> 5;         // which of the wave's 2 matrices
  const int g = lane & 15;           // pair group
  const int sub = (lane >> 4) & 1;   // row half
  const int off = sub * 16;

  const bool is_g0 = (g == 0);
  // initial columns: g==0 -> {31, 0}; else {g, 31-g}
  const int p0 = is_g0 ? 31 : g;
  const int q0 = is_g0 ? 0 : 31 - g;

  const size_t gbase = (size_t)blockIdx.x * 8 + wid * 2;
  const float* A = P + (gbase + mat) * kMSZ;

  float cp[16], cq[16];
  {  // A is symmetric: column c == row c (row-major, 32 floats)
    const float* pr = A + p0 * 32 + off;
    const float* qr = A + q0 * 32 + off;
#pragma unroll
    for (int i = 0; i < 16; i += 4) {
      const float4 a = CF4(pr + i);
      cp[i] = a.x; cp[i + 1] = a.y; cp[i + 2] = a.z; cp[i + 3] = a.w;
      const float4 b = CF4(qr + i);
      cq[i] = b.x; cq[i + 1] = b.y; cq[i + 2] = b.z; cq[i + 3] = b.w;
    }
  }
  // initial squared norms (reduce across the 2 subs: lanes l, l^16)
  float app = 0.f, aqq = 0.f;
#pragma unroll
  for (int i = 0; i < 16; ++i) {
    app = fmaf(cp[i], cp[i], app);
    aqq = fmaf(cq[i], cq[i], aqq);
  }
  app += __shfl_xor(app, 16);
  aqq += __shfl_xor(aqq, 16);

  for (int sw = 0; sw < kNSweep; ++sw) {
    for (int r = 0; r < 31; ++r) {
      // apq = colp . colq (two FMA chains for ILP, then cross-sub reduce)
      float d0 = cp[0] * cq[0], d1 = cp[1] * cq[1];
#pragma unroll
      for (int i = 2; i < 16; i += 2) {
        d0 = fmaf(cp[i], cq[i], d0);
        d1 = fmaf(cp[i + 1], cq[i + 1], d1);
      }
      float apq = d0 + d1;
      apq += __shfl_xor(apq, 16);
      // rotation from (d, apq) with 3 transcendentals (validated R9/R11):
      //   h = sqrt(d^2 + 4 apq^2); t = sgn(d) * 2 apq / (|d| + h)
      //   c = rsq(1+t^2); s = t*c.   apq==0 -> t=0 -> exact identity.
      const float d = aqq - app;
      const float apq2 = 2.f * apq;
      float h2 = fmaf(d, d, apq2 * apq2);
      h2 = fmaxf(h2, 1e-38f);  // guard d=apq=0
      const float hr = __builtin_amdgcn_rsqf(h2);
      const float h = h2 * hr;
      const float den = fabsf(d) + h;
      const float t0 = apq2 * __builtin_amdgcn_rcpf(den);
      const float tt = xsign(t0, d);
      const float c = __builtin_amdgcn_rsqf(fmaf(tt, tt, 1.f));
      const float sn = tt * c;
      // fused rotate + ring exchange (R5 DPP semantics, loop-local temps)
#pragma unroll
      for (int i = 0; i < 16; ++i) {
        const float t1 = c * cp[i];
        const float t2 = sn * cp[i];
        const float np_ = fmaf(-sn, cq[i], t1);
        const float nq_ = fmaf(c, cq[i], t2);
        const float cpm = updppf<kShl1>(nq_, np_);
        cp[i] = is_g0 ? np_ : cpm;
        cq[i] = updppf<kShr1>(cpm, nq_);
      }
      // analytic norm update (rotation preserves app+aqq; np.nq == 0)
      const float c2 = c * c, s2 = sn * sn, cs2 = 2.f * c * sn;
      const float capp = fmaf(c2, app, fmaf(s2, aqq, -cs2 * apq));
      const float caqq = (app + aqq) - capp;
      {
        const float capm = updppf<kShl1>(caqq, capp);
        app = is_g0 ? capp : capm;
        aqq = updppf<kShr1>(capm, caqq);
      }
    }
  }
  // ---- epilogue ----
  // exact column norms in-register (this lane's half + partner's half)
  float ssp = 0.f, ssq = 0.f;
#pragma unroll
  for (int i = 0; i < 16; ++i) {
    ssp = fmaf(cp[i], cp[i], ssp);
    ssq = fmaf(cq[i], cq[i], ssq);
  }
  ssp += __shfl_xor(ssp, 16);
  ssq += __shfl_xor(ssq, 16);
  const float lgp = 0.5f * logf(ssp);   // log sigma_p
  const float lgq = 0.5f * logf(ssq);
  const float wp = lgp * __builtin_amdgcn_rcpf(ssp);
  const float wq = lgq * __builtin_amdgcn_rcpf(ssq);
  {  // sumsq = sum over pairs (lgp^2 + lgq^2); reduce over g within 16-row
    float tot = fmaf(lgp, lgp, lgq * lgq);
    tot += __shfl_xor(tot, 1); tot += __shfl_xor(tot, 2);
    tot += __shfl_xor(tot, 4); tot += __shfl_xor(tot, 8);
    if ((lane & 31) == 0) sq[gbase + mat] = tot;
  }
  // sequential per-matrix epilogue: half-wave m dumps its columns+weights to
  // the wave's LDS slot, then the FULL wave computes log A = B diag(w) B^T.
  float* Bs = lds + wid * kJSlot;
  float* ncol = Bs + 1152;
  for (int m = 0; m < 2; ++m) {
    __builtin_amdgcn_wave_barrier();
    if (mat == m) {
#pragma unroll
      for (int i = 0; i < 16; i += 4) {
        F4(&Bs[p0 * 36 + off + i]) = make_float4(cp[i], cp[i+1], cp[i+2], cp[i+3]);
        F4(&Bs[q0 * 36 + off + i]) = make_float4(cq[i], cq[i+1], cq[i+2], cq[i+3]);
      }
      if (sub == 0) {
        ncol[p0] = wp;
        ncol[q0] = wq;
      }
    }
    __builtin_amdgcn_wave_barrier();
    {  // log A = B diag(w) B^T, 4x4 tile per lane, write back (row-major)
      float* Am = P + (gbase + m) * kMSZ;
      const int rr = (lane >> 3) * 4, cc = (lane & 7) * 4;
      float acc[4][4] = {};
      for (int c = 0; c < 32; ++c) {
        const float w = ncol[c];
        const float4 br = CF4(&Bs[c * 36 + rr]);
        const float4 bc = CF4(&Bs[c * 36 + cc]);
        const float wr[4]  = {w * br.x, w * br.y, w * br.z, w * br.w};
        const float bcv[4] = {bc.x, bc.y, bc.z, bc.w};
#pragma unroll
        for (int i = 0; i < 4; ++i)
#pragma unroll
          for (int j2 = 0; j2 < 4; ++j2) acc[i][j2] += wr[i] * bcv[j2];
      }
#pragma unroll
      for (int i = 0; i < 4; ++i)
        F4(&Am[(rr + i) * 32 + cc]) =
            make_float4(acc[i][0], acc[i][1], acc[i][2], acc[i][3]);
    }
    __builtin_amdgcn_wave_barrier();
  }
}

// ------------------------------------------------- scores/softmax/attn ----
// Block: (jt, b), 16-wide j tile -> 256 blocks (1/CU). K-chunk staged
// TRANSPOSED [k][i] so i-fragments are ds_read_b128; Q [k][j] -> b64.
__global__ __launch_bounds__(256) void k_attn(
    const float* __restrict__ P, const float* __restrict__ sq,
    float* __restrict__ attn) {
  __shared__ float Kt[32 * 132];   // [k][i], padded
  __shared__ float Qt[32 * 20];    // [k][j], padded
  __shared__ float Ss[128 * 20];   // scores [i][j]
  __shared__ float red[16 * 20];
  __shared__ float mcol[16];
  __shared__ float scol[16];
  const int t = threadIdx.x;
  const int b = blockIdx.y, jt = blockIdx.x;
  const int j0g = jt * 16;
  const float* logK = P + ((size_t)kNMAT + (size_t)b * kM) * kMSZ;
  const float* logQ = P + ((size_t)b * kM + j0g) * kMSZ;
  const int i0 = (t >> 3) * 4, j0 = (t & 7) * 2;
  float acc[4][2] = {};
  for (int dc = 0; dc < kMSZ; dc += 32) {
    __syncthreads();
    {  // stage Kt[k][i]: row r of logK, cols dc+c0..+15, transposed write
      const int r = t >> 1, c0 = (t & 1) * 16;
      const float* src = logK + (size_t)r * kMSZ + dc + c0;
#pragma unroll
      for (int ii = 0; ii < 16; ii += 4) {
        const float4 v = CF4(src + ii);
        Kt[(c0 + ii + 0) * 132 + r] = v.x;
        Kt[(c0 + ii + 1) * 132 + r] = v.y;
        Kt[(c0 + ii + 2) * 132 + r] = v.z;
        Kt[(c0 + ii + 3) * 132 + r] = v.w;
      }
    }
    {  // stage Qt[k][j]
      const int j = t >> 4, c0 = (t & 15) * 2;
      const float2 v = *(const float2*)(logQ + (size_t)j * kMSZ + dc + c0);
      Qt[(c0 + 0) * 20 + j] = v.x;
      Qt[(c0 + 1) * 20 + j] = v.y;
    }
    __syncthreads();
    for (int k = 0; k < 32; ++k) {
      const float4 kv = CF4(&Kt[k * 132 + i0]);
      const float2 qv = *(const float2*)&Qt[k * 20 + j0];
      acc[0][0] = fmaf(kv.x, qv.x, acc[0][0]);
      acc[0][1] = fmaf(kv.x, qv.y, acc[0][1]);
      acc[1][0] = fmaf(kv.y, qv.x, acc[1][0]);
      acc[1][1] = fmaf(kv.y, qv.y, acc[1][1]);
      acc[2][0] = fmaf(kv.z, qv.x, acc[2][0]);
      acc[2][1] = fmaf(kv.z, qv.y, acc[2][1]);
      acc[3][0] = fmaf(kv.w, qv.x, acc[3][0]);
      acc[3][1] = fmaf(kv.w, qv.y, acc[3][1]);
    }
  }
  {  // energy -> scores, into Ss[i][j]
    float k2v[4], q2v[2];
#pragma unroll
    for (int i = 0; i < 4; ++i) k2v[i] = sq[kNMAT + b * kM + i0 + i];
#pragma unroll
    for (int j2 = 0; j2 < 2; ++j2) q2v[j2] = sq[b * kM + j0g + j0 + j2];
#pragma unroll
    for (int i = 0; i < 4; ++i)
#pragma unroll
      for (int j2 = 0; j2 < 2; ++j2) {
        float e = k2v[i] + q2v[j2] - 2.f * acc[i][j2];
        e = fmaxf(e, 0.f);
        Ss[(i0 + i) * 20 + (j0 + j2)] = 1.f / (1.f + log1pf(e));
      }
  }
  __syncthreads();
  const int jl = t & 15, grp = t >> 4;  // 16 groups x 16 j-cols; group: 8 i-rows
  {
    float m = -1e30f;
#pragma unroll
    for (int i = 0; i < 8; ++i) m = fmaxf(m, Ss[(grp * 8 + i) * 20 + jl]);
    red[grp * 20 + jl] = m;
  }
  __syncthreads();
  if (t < 16) {
    float m = red[t];
#pragma unroll
    for (int g = 1; g < 16; ++g) m = fmaxf(m, red[g * 20 + t]);
    mcol[t] = m;
  }
  __syncthreads();
  {
    const float mj = mcol[jl];
    float s = 0.f;
#pragma unroll
    for (int i = 0; i < 8; ++i) s += expf(Ss[(grp * 8 + i) * 20 + jl] - mj);
    red[grp * 20 + jl] = s;
  }
  __syncthreads();
  if (t < 16) {
    float s = red[t];
#pragma unroll
    for (int g = 1; g < 16; ++g) s += red[g * 20 + t];
    scol[t] = 1.f / s;
  }
  __syncthreads();
  {  // write attn[b][j][i], coalesced in i
    const int il = t & 31, jg = t >> 5;
#pragma unroll
    for (int rep = 0; rep < 2; ++rep) {
      const int j2 = jg + rep * 8;
      const float mj = mcol[j2], is = scol[j2];
      float* dst = attn + ((size_t)b * kM + j0g + j2) * kM;
#pragma unroll
      for (int c4 = 0; c4 < 4; ++c4) {
        const int i = il + c4 * 32;
        dst[i] = expf(Ss[i * 20 + j2] - mj) * is;
      }
    }
  }
}

// -------------------------------------------------------------- meanlog ----
// ML[b][j][:] = sum_i attn[b][j][i] * logV[b][i][:]. Block: (jt, b), 16 j.
// All 16 j-accumulators in registers (thread owns 4 d-cols); attn weights
// broadcast from LDS (b128 per 4k); V streamed from global (L2-resident).
__global__ __launch_bounds__(256) void k_meanlog(
    const float* __restrict__ attn, const float* __restrict__ P,
    float* __restrict__ ML) {
  __shared__ float As[16 * 132];
  const int t = threadIdx.x;
  const int b = blockIdx.y, jt = blockIdx.x;
  const int j0g = jt * 16;
  const float* logV = P + ((size_t)2 * kNMAT + (size_t)b * kM) * kMSZ;
  {  // stage attn tile [16][128]
    const int j = t >> 4, k0 = (t & 15) * 8;
    const float* src = attn + ((size_t)b * kM + j0g + j) * kM + k0;
    F4(&As[j * 132 + k0])     = CF4(src);
    F4(&As[j * 132 + k0 + 4]) = CF4(src + 4);
  }
  __syncthreads();
  const int d0 = t * 4;
  float acc[16][4] = {};
  for (int k = 0; k < kM; k += 4) {
    float4 vr[4];
#pragma unroll
    for (int kk = 0; kk < 4; ++kk)
      vr[kk] = CF4(&logV[(size_t)(k + kk) * kMSZ + d0]);
#pragma unroll
    for (int j = 0; j < 16; ++j) {
      const float4 w = CF4(&As[j * 132 + k]);
      const float wv[4] = {w.x, w.y, w.z, w.w};
#pragma unroll
      for (int kk = 0; kk < 4; ++kk) {
        const float* vv = (const float*)&vr[kk];
#pragma unroll
        for (int dd = 0; dd < 4; ++dd)
          acc[j][dd] = fmaf(wv[kk], vv[dd], acc[j][dd]);
      }
    }
  }
#pragma unroll
  for (int j = 0; j < 16; ++j)
    F4(&ML[((size_t)b * kM + j0g + j) * kMSZ + d0]) =
        make_float4(acc[j][0], acc[j][1], acc[j][2], acc[j][3]);
}

// ------------------------------------------------------------------ exp ----
// out = exp(S): scaling-and-squaring + degree-7 Horner Taylor (||M||<=0.5
// after scaling -> truncation 1.6e-7, invisible vs the 0.0039 floor).
// 4 waves/block, one matrix per wave, private LDS slot, no s_barrier.
// M and T are SYMMETRIC, so row-fragments load as b128 from [k][r].
constexpr int kESlot = 2 * 1152;  // Mb + Tb

__global__ __launch_bounds__(256) void k_expm(const float* __restrict__ ML,
                                              float* __restrict__ out) {
  __shared__ float lds[4 * kESlot];
  const int t = threadIdx.x;
  const int wid = t >> 6, lane = t & 63;
  const size_t bm = (size_t)blockIdx.x * 4 + wid;
  float* Mb = lds + wid * kESlot;
  float* Tb = Mb + 1152;
  const float* S = ML + bm * kMSZ;
  const int r = lane >> 1, c0 = (lane & 1) * 16;
  float4 v0 = CF4(S + r * 32 + c0),     v1 = CF4(S + r * 32 + c0 + 4),
         v2 = CF4(S + r * 32 + c0 + 8), v3 = CF4(S + r * 32 + c0 + 12);
  float lsum = v0.x*v0.x + v0.y*v0.y + v0.z*v0.z + v0.w*v0.w
             + v1.x*v1.x + v1.y*v1.y + v1.z*v1.z + v1.w*v1.w
             + v2.x*v2.x + v2.y*v2.y + v2.z*v2.z + v2.w*v2.w
             + v3.x*v3.x + v3.y*v3.y + v3.z*v3.z + v3.w*v3.w;
#pragma unroll
  for (int d = 1; d < 64; d <<= 1) lsum += __shfl_xor(lsum, d);
  const float fn = sqrtf(lsum);     // Frobenius norm >= spectral norm
  int sc = 0;
  if (fn > 0.5f) sc = (int)ceilf(log2f(fn * 2.0f));
  const float scale = exp2f((float)(-sc));
  v0.x*=scale; v0.y*=scale; v0.z*=scale; v0.w*=scale;
  v1.x*=scale; v1.y*=scale; v1.z*=scale; v1.w*=scale;
  v2.x*=scale; v2.y*=scale; v2.z*=scale; v2.w*=scale;
  v3.x*=scale; v3.y*=scale; v3.z*=scale; v3.w*=scale;
  F4(&Mb[r * 36 + c0])      = v0;
  F4(&Mb[r * 36 + c0 + 4])  = v1;
  F4(&Mb[r * 36 + c0 + 8])  = v2;
  F4(&Mb[r * 36 + c0 + 12]) = v3;
  __builtin_amdgcn_wave_barrier();
  const int rr = (lane >> 3) * 4, cc = (lane & 7) * 4;
#pragma unroll
  for (int i = 0; i < 4; ++i) {  // T = I + M/7
    float4 v = F4(&Mb[(rr + i) * 36 + cc]);
    v.x = v.x * (1.f/7.f) + ((rr + i == cc + 0) ? 1.f : 0.f);
    v.y = v.y * (1.f/7.f) + ((rr + i == cc + 1) ? 1.f : 0.f);
    v.z = v.z * (1.f/7.f) + ((rr + i == cc + 2) ? 1.f : 0.f);
    v.w = v.w * (1.f/7.f) + ((rr + i == cc + 3) ? 1.f : 0.f);
    F4(&Tb[(rr + i) * 36 + cc]) = v;
  }
  __builtin_amdgcn_wave_barrier();
  for (int j = 6; j >= 1; --j) {  // T <- I + (M*T)/j, in place
    float a4[4][4] = {};
    for (int k = 0; k < 32; ++k) {
      const float4 mv = CF4(&Mb[k * 36 + rr]);  // M[rr..rr+3][k] by symmetry
      const float mvv[4] = {mv.x, mv.y, mv.z, mv.w};
      const float4 tv = CF4(&Tb[k * 36 + cc]);
      const float tvv[4] = {tv.x, tv.y, tv.z, tv.w};
#pragma unroll
      for (int i = 0; i < 4; ++i)
#pragma unroll
        for (int j2 = 0; j2 < 4; ++j2) a4[i][j2] += mvv[i] * tvv[j2];
    }
    const float inv = 1.f / (float)j;
#pragma unroll
    for (int i = 0; i < 4; ++i) {
      float4 v;
      v.x = a4[i][0] * inv + ((rr + i == cc + 0) ? 1.f : 0.f);
      v.y = a4[i][1] * inv + ((rr + i == cc + 1) ? 1.f : 0.f);
      v.z = a4[i][2] * inv + ((rr + i == cc + 2) ? 1.f : 0.f);
      v.w = a4[i][3] * inv + ((rr + i == cc + 3) ? 1.f : 0.f);
      F4(&Tb[(rr + i) * 36 + cc]) = v;
    }
    __builtin_amdgcn_wave_barrier();
  }
  for (int st = 0; st < sc; ++st) {  // T <- T*T, in place (T symmetric)
    float a4[4][4] = {};
    for (int k = 0; k < 32; ++k) {
      const float4 mv = CF4(&Tb[k * 36 + rr]);  // T[rr..rr+3][k] by symmetry
      const float mvv[4] = {mv.x, mv.y, mv.z, mv.w};
      const float4 tv = CF4(&Tb[k * 36 + cc]);
      const float tvv[4] = {tv.x, tv.y, tv.z, tv.w};
#pragma unroll
      for (int i = 0; i < 4; ++i)
#pragma unroll
        for (int j2 = 0; j2 < 4; ++j2) a4[i][j2] += mvv[i] * tvv[j2];
    }
#pragma unroll
    for (int i = 0; i < 4; ++i)
      F4(&Tb[(rr + i) * 36 + cc]) =
          make_float4(a4[i][0], a4[i][1], a4[i][2], a4[i][3]);
    __builtin_amdgcn_wave_barrier();
  }
#pragma unroll
  for (int i = 0; i < 4; ++i) {
    const float4 v = CF4(&Tb[(rr + i) * 36 + cc]);
    F4(&out[bm * kMSZ + (rr + i) * 32 + cc]) = v;
  }
}

// -------------------------------------------------------------- launch ----
extern "C" void kernel_launch(void* const* d_in, const int* in_sizes, int n_in,
                              void* d_out, int out_size, void* d_ws, size_t ws_size,
                              hipStream_t stream) {
  const float* x  = (const float*)d_in[0];
  const float* Wq = (const float*)d_in[1];
  const float* Wk = (const float*)d_in[2];
  const float* Wv = (const float*)d_in[3];
  float* ws   = (float*)d_ws;
  float* P    = ws;                 // [3][4096][1024]
  float* sq   = ws + OFF_SS;        // [3][4096]
  float* attn = ws + OFF_ATTN;      // [32][128][128]
  float* ML   = ws;                 // reuse logQ region (dead after k_attn)
  float* out  = (float*)d_out;

  k_bimap<<<kNMAT, 256, 0, stream>>>(x, Wq, Wk, Wv, P);
  k_jacobi_log<<<3 * kNMAT / 8, 256, 0, stream>>>(P, sq);
  k_attn<<<dim3(8, kBS), 256, 0, stream>>>(P, sq, attn);
  k_meanlog<<<dim3(8, kBS), 256, 0, stream>>>(attn, P, ML);
  k_expm<<<kNMAT / 4, 256, 0, stream>>>(ML, out);
}

// Round 14
// 442.406 us; speedup vs baseline: 1.2576x; 1.0237x over previous
//
#include <hip/hip_runtime.h>
#include <math.h>

// Problem constants
constexpr int kBS = 32, kM = 128, kNMAT = kBS * kM;         // 4096 (b,m) pairs
constexpr int kDIN = 64, kDOUT = 32, kMSZ = kDOUT * kDOUT;  // 1024 floats per 32x32
// Jacobi rounds: the Brent-Luk ring needs NO whole-sweep alignment — the
// epilogue sum log A = sum_c w_c b_c b_c^T is permutation-invariant over
// columns, and each lane always holds 2 distinct columns. 124 rounds
// (4 sweeps) measured absmax 0.0156 (passed); 155 (5 sweeps) -> 0.0039
// (bf16 floor). 140 rounds is bounded by both: >= 4-sweep accuracy.
constexpr int kNRounds = 140;

// ws layout (floats):
//   P/log : [3][4096][1024]  (Q=0,K=1,V=2; overwritten in place by logs)
//   sumsq : [3][4096]        (||log||_F^2 per matrix)
// mean_log reuses the logQ region (dead after k_attn_meanlog reads logQ).
constexpr size_t OFF_SS   = (size_t)3 * kNMAT * kMSZ;

#define F4(p)  (*(float4*)(p))
#define CF4(p) (*(const float4*)(p))

// ---------------------------------------------------------------- bimap ----
// P_t = W_t^T X W_t for t in {Q,K,V}; one block per (b,m).
__global__ __launch_bounds__(256) void k_bimap(
    const float* __restrict__ x, const float* __restrict__ Wq,
    const float* __restrict__ Wk, const float* __restrict__ Wv,
    float* __restrict__ P) {
  __shared__ float Xs[64 * 68];   // X, row-major padded
  __shared__ float Wsh[64 * 32];  // current W, row-major
  __shared__ float Ts[64 * 36];   // T = X*W, padded
  const int t = threadIdx.x;
  const int bm = blockIdx.x;
  const float* xp = x + (size_t)bm * (kDIN * kDIN);
  {
    const int f0 = t * 16;
    const int r = f0 >> 6, c = f0 & 63;
    const float* src = xp + f0;
    float* dst = &Xs[r * 68 + c];
#pragma unroll
    for (int i = 0; i < 4; ++i) F4(dst + 4 * i) = CF4(src + 4 * i);
  }
  const int r0 = (t >> 3) * 2;   // stage-1 rows
  const int j0 = (t & 7) * 4;    // output cols
  const int i2 = t >> 3;         // stage-2 row
  for (int tt = 0; tt < 3; ++tt) {
    const float* W = (tt == 0) ? Wq : ((tt == 1) ? Wk : Wv);
    __syncthreads();  // protect Wsh/Ts from previous type (also covers Xs @ tt=0)
    F4(&Wsh[t * 8]) = CF4(W + t * 8);
    F4(&Wsh[t * 8 + 4]) = CF4(W + t * 8 + 4);
    __syncthreads();
    // stage 1: T = X * W   (64x32). X symmetric: X[r0][k] = Xs[k][r0] -> b64.
    float a0[4] = {0.f, 0.f, 0.f, 0.f}, a1[4] = {0.f, 0.f, 0.f, 0.f};
    for (int k = 0; k < 64; ++k) {
      const float2 x01 = *(const float2*)&Xs[k * 68 + r0];
      const float4 w = CF4(&Wsh[k * 32 + j0]);
      a0[0] += x01.x * w.x; a0[1] += x01.x * w.y; a0[2] += x01.x * w.z; a0[3] += x01.x * w.w;
      a1[0] += x01.y * w.x; a1[1] += x01.y * w.y; a1[2] += x01.y * w.z; a1[3] += x01.y * w.w;
    }
    F4(&Ts[r0 * 36 + j0])       = make_float4(a0[0], a0[1], a0[2], a0[3]);
    F4(&Ts[(r0 + 1) * 36 + j0]) = make_float4(a1[0], a1[1], a1[2], a1[3]);
    __syncthreads();
    // stage 2: P = W^T * T  (32x32)
    float b4[4] = {0.f, 0.f, 0.f, 0.f};
    for (int p = 0; p < 64; ++p) {
      const float wv = Wsh[p * 32 + i2];
      const float4 tv = CF4(&Ts[p * 36 + j0]);
      b4[0] += wv * tv.x; b4[1] += wv * tv.y; b4[2] += wv * tv.z; b4[3] += wv * tv.w;
    }
    F4(&P[((size_t)tt * kNMAT + bm) * kMSZ + i2 * 32 + j0]) =
        make_float4(b4[0], b4[1], b4[2], b4[3]);
  }
}

// ----------------------------------------------------- one-sided Jacobi ----
// Register-resident Brent-Luk one-sided Jacobi, TWO matrices per wave
// (mat = lane>>5), g = lane&15 (pair group), sub = (lane>>4)&1 (row half,
// 16 scalar elems/lane). Round-loop = R5 verbatim + fused loop-local temps
// (R13: 284 us, VGPR 64, clean HBM counters). Flat round loop — the body
// has no dependence on the round index.
constexpr int kJSlot = 32 * 36 + 32;  // 1152 col data + 32 weights = 1184 floats
constexpr int kShl1 = 0x101, kShr1 = 0x111;

template <int CTRL>
__device__ __forceinline__ float updppf(float old_, float x) {
  return __builtin_bit_cast(float,
      __builtin_amdgcn_update_dpp(__builtin_bit_cast(int, old_),
                                  __builtin_bit_cast(int, x),
                                  CTRL, 0xf, 0xf, false));
}

__device__ __forceinline__ float xsign(float x, float s) {  // x * sgn(s)
  return __builtin_bit_cast(float,
      __builtin_bit_cast(int, x) ^
      (__builtin_bit_cast(int, s) & 0x80000000));
}

__global__ __launch_bounds__(256, 4) void k_jacobi_log(float* __restrict__ P,
                                                       float* __restrict__ sq) {
  __shared__ float lds[4 * kJSlot];  // ONE slot per wave, reused per matrix
  const int t = threadIdx.x;
  const int wid = t >> 6, lane = t & 63;
  const int mat = lane >> 5;         // which of the wave's 2 matrices
  const int g = lane & 15;           // pair group
  const int sub = (lane >> 4) & 1;   // row half
  const int off = sub * 16;

  const bool is_g0 = (g == 0);
  // initial columns: g==0 -> {31, 0}; else {g, 31-g}
  const int p0 = is_g0 ? 31 : g;
  const int q0 = is_g0 ? 0 : 31 - g;

  const size_t gbase = (size_t)blockIdx.x * 8 + wid * 2;
  const float* A = P + (gbase + mat) * kMSZ;

  float cp[16], cq[16];
  {  // A is symmetric: column c == row c (row-major, 32 floats)
    const float* pr = A + p0 * 32 + off;
    const float* qr = A + q0 * 32 + off;
#pragma unroll
    for (int i = 0; i < 16; i += 4) {
      const float4 a = CF4(pr + i);
      cp[i] = a.x; cp[i + 1] = a.y; cp[i + 2] = a.z; cp[i + 3] = a.w;
      const float4 b = CF4(qr + i);
      cq[i] = b.x; cq[i + 1] = b.y; cq[i + 2] = b.z; cq[i + 3] = b.w;
    }
  }
  // initial squared norms (reduce across the 2 subs: lanes l, l^16)
  float app = 0.f, aqq = 0.f;
#pragma unroll
  for (int i = 0; i < 16; ++i) {
    app = fmaf(cp[i], cp[i], app);
    aqq = fmaf(cq[i], cq[i], aqq);
  }
  app += __shfl_xor(app, 16);
  aqq += __shfl_xor(aqq, 16);

  for (int rnd = 0; rnd < kNRounds; ++rnd) {
    // apq = colp . colq (two FMA chains for ILP, then cross-sub reduce)
    float d0 = cp[0] * cq[0], d1 = cp[1] * cq[1];
#pragma unroll
    for (int i = 2; i < 16; i += 2) {
      d0 = fmaf(cp[i], cq[i], d0);
      d1 = fmaf(cp[i + 1], cq[i + 1], d1);
    }
    float apq = d0 + d1;
    apq += __shfl_xor(apq, 16);
    // rotation from (d, apq) with 3 transcendentals (validated R9/R11):
    //   h = sqrt(d^2 + 4 apq^2); t = sgn(d) * 2 apq / (|d| + h)
    //   c = rsq(1+t^2); s = t*c.   apq==0 -> t=0 -> exact identity.
    const float d = aqq - app;
    const float apq2 = 2.f * apq;
    float h2 = fmaf(d, d, apq2 * apq2);
    h2 = fmaxf(h2, 1e-38f);  // guard d=apq=0
    const float hr = __builtin_amdgcn_rsqf(h2);
    const float h = h2 * hr;
    const float den = fabsf(d) + h;
    const float t0 = apq2 * __builtin_amdgcn_rcpf(den);
    const float tt = xsign(t0, d);
    const float c = __builtin_amdgcn_rsqf(fmaf(tt, tt, 1.f));
    const float sn = tt * c;
    // fused rotate + ring exchange (R5 DPP semantics, loop-local temps)
#pragma unroll
    for (int i = 0; i < 16; ++i) {
      const float t1 = c * cp[i];
      const float t2 = sn * cp[i];
      const float np_ = fmaf(-sn, cq[i], t1);
      const float nq_ = fmaf(c, cq[i], t2);
      const float cpm = updppf<kShl1>(nq_, np_);
      cp[i] = is_g0 ? np_ : cpm;
      cq[i] = updppf<kShr1>(cpm, nq_);
    }
    // analytic norm update (rotation preserves app+aqq; np.nq == 0)
    const float c2 = c * c, s2 = sn * sn, cs2 = 2.f * c * sn;
    const float capp = fmaf(c2, app, fmaf(s2, aqq, -cs2 * apq));
    const float caqq = (app + aqq) - capp;
    {
      const float capm = updppf<kShl1>(caqq, capp);
      app = is_g0 ? capp : capm;
      aqq = updppf<kShr1>(capm, caqq);
    }
  }
  // ---- epilogue ---- (column positions are a permutation of 0..31; the
  // weighted outer-product sum is permutation-invariant, so fixed p0/q0
  // slot assignments are correct at ANY round count)
  float ssp = 0.f, ssq = 0.f;
#pragma unroll
  for (int i = 0; i < 16; ++i) {
    ssp = fmaf(cp[i], cp[i], ssp);
    ssq = fmaf(cq[i], cq[i], ssq);
  }
  ssp += __shfl_xor(ssp, 16);
  ssq += __shfl_xor(ssq, 16);
  const float lgp = 0.5f * logf(ssp);   // log sigma_p
  const float lgq = 0.5f * logf(ssq);
  const float wp = lgp * __builtin_amdgcn_rcpf(ssp);
  const float wq = lgq * __builtin_amdgcn_rcpf(ssq);
  {  // sumsq = sum over pairs (lgp^2 + lgq^2); reduce over g within 16-row
    float tot = fmaf(lgp, lgp, lgq * lgq);
    tot += __shfl_xor(tot, 1); tot += __shfl_xor(tot, 2);
    tot += __shfl_xor(tot, 4); tot += __shfl_xor(tot, 8);
    if ((lane & 31) == 0) sq[gbase + mat] = tot;
  }
  // sequential per-matrix epilogue: half-wave m dumps its columns+weights to
  // the wave's LDS slot, then the FULL wave computes log A = B diag(w) B^T.
  float* Bs = lds + wid * kJSlot;
  float* ncol = Bs + 1152;
  for (int m = 0; m < 2; ++m) {
    __builtin_amdgcn_wave_barrier();
    if (mat == m) {
#pragma unroll
      for (int i = 0; i < 16; i += 4) {
        F4(&Bs[p0 * 36 + off + i]) = make_float4(cp[i], cp[i+1], cp[i+2], cp[i+3]);
        F4(&Bs[q0 * 36 + off + i]) = make_float4(cq[i], cq[i+1], cq[i+2], cq[i+3]);
      }
      if (sub == 0) {
        ncol[p0] = wp;
        ncol[q0] = wq;
      }
    }
    __builtin_amdgcn_wave_barrier();
    {  // log A = B diag(w) B^T, 4x4 tile per lane, write back (row-major)
      float* Am = P + (gbase + m) * kMSZ;
      const int rr = (lane >> 3) * 4, cc = (lane & 7) * 4;
      float acc[4][4] = {};
      for (int c = 0; c < 32; ++c) {
        const float w = ncol[c];
        const float4 br = CF4(&Bs[c * 36 + rr]);
        const float4 bc = CF4(&Bs[c * 36 + cc]);
        const float wr[4]  = {w * br.x, w * br.y, w * br.z, w * br.w};
        const float bcv[4] = {bc.x, bc.y, bc.z, bc.w};
#pragma unroll
        for (int i = 0; i < 4; ++i)
#pragma unroll
          for (int j2 = 0; j2 < 4; ++j2) acc[i][j2] += wr[i] * bcv[j2];
      }
#pragma unroll
      for (int i = 0; i < 4; ++i)
        F4(&Am[(rr + i) * 32 + cc]) =
            make_float4(acc[i][0], acc[i][1], acc[i][2], acc[i][3]);
    }
    __builtin_amdgcn_wave_barrier();
  }
}

// ------------------------------------------ fused scores/softmax/meanlog ----
// Block: (jt, b), 16-wide j tile -> 256 blocks (1/CU). Phase 1: scores via
// transposed K staging (ds_read_b128 fragments). Phase 2: softmax over i.
// Phase 3: normalized attn kept in LDS (As[16][132], exactly the meanlog
// staging layout — no global round-trip), then ML = attn @ logV with all 16
// j-accumulators in registers and V streamed from global (L2-resident).
__global__ __launch_bounds__(256) void k_attn_meanlog(
    const float* __restrict__ P, const float* __restrict__ sq,
    float* __restrict__ ML) {
  __shared__ float Kt[32 * 132];   // [k][i], padded
  __shared__ float Qt[32 * 20];    // [k][j], padded
  __shared__ float Ss[128 * 20];   // scores [i][j]
  __shared__ float red[16 * 20];
  __shared__ float mcol[16];
  __shared__ float scol[16];
  __shared__ float As[16 * 132];   // normalized attn [j][i]
  const int t = threadIdx.x;
  const int b = blockIdx.y, jt = blockIdx.x;
  const int j0g = jt * 16;
  const float* logK = P + ((size_t)kNMAT + (size_t)b * kM) * kMSZ;
  const float* logQ = P + ((size_t)b * kM + j0g) * kMSZ;
  const int i0 = (t >> 3) * 4, j0 = (t & 7) * 2;
  float acc[4][2] = {};
  for (int dc = 0; dc < kMSZ; dc += 32) {
    __syncthreads();
    {  // stage Kt[k][i]: row r of logK, cols dc+c0..+15, transposed write
      const int r = t >> 1, c0 = (t & 1) * 16;
      const float* src = logK + (size_t)r * kMSZ + dc + c0;
#pragma unroll
      for (int ii = 0; ii < 16; ii += 4) {
        const float4 v = CF4(src + ii);
        Kt[(c0 + ii + 0) * 132 + r] = v.x;
        Kt[(c0 + ii + 1) * 132 + r] = v.y;
        Kt[(c0 + ii + 2) * 132 + r] = v.z;
        Kt[(c0 + ii + 3) * 132 + r] = v.w;
      }
    }
    {  // stage Qt[k][j]
      const int j = t >> 4, c0 = (t & 15) * 2;
      const float2 v = *(const float2*)(logQ + (size_t)j * kMSZ + dc + c0);
      Qt[(c0 + 0) * 20 + j] = v.x;
      Qt[(c0 + 1) * 20 + j] = v.y;
    }
    __syncthreads();
    for (int k = 0; k < 32; ++k) {
      const float4 kv = CF4(&Kt[k * 132 + i0]);
      const float2 qv = *(const float2*)&Qt[k * 20 + j0];
      acc[0][0] = fmaf(kv.x, qv.x, acc[0][0]);
      acc[0][1] = fmaf(kv.x, qv.y, acc[0][1]);
      acc[1][0] = fmaf(kv.y, qv.x, acc[1][0]);
      acc[1][1] = fmaf(kv.y, qv.y, acc[1][1]);
      acc[2][0] = fmaf(kv.z, qv.x, acc[2][0]);
      acc[2][1] = fmaf(kv.z, qv.y, acc[2][1]);
      acc[3][0] = fmaf(kv.w, qv.x, acc[3][0]);
      acc[3][1] = fmaf(kv.w, qv.y, acc[3][1]);
    }
  }
  {  // energy -> scores, into Ss[i][j]
    float k2v[4], q2v[2];
#pragma unroll
    for (int i = 0; i < 4; ++i) k2v[i] = sq[kNMAT + b * kM + i0 + i];
#pragma unroll
    for (int j2 = 0; j2 < 2; ++j2) q2v[j2] = sq[b * kM + j0g + j0 + j2];
#pragma unroll
    for (int i = 0; i < 4; ++i)
#pragma unroll
      for (int j2 = 0; j2 < 2; ++j2) {
        float e = k2v[i] + q2v[j2] - 2.f * acc[i][j2];
        e = fmaxf(e, 0.f);
        Ss[(i0 + i) * 20 + (j0 + j2)] = 1.f / (1.f + log1pf(e));
      }
  }
  __syncthreads();
  const int jl = t & 15, grp = t >> 4;  // 16 groups x 16 j-cols; group: 8 i-rows
  {
    float m = -1e30f;
#pragma unroll
    for (int i = 0; i < 8; ++i) m = fmaxf(m, Ss[(grp * 8 + i) * 20 + jl]);
    red[grp * 20 + jl] = m;
  }
  __syncthreads();
  if (t < 16) {
    float m = red[t];
#pragma unroll
    for (int g = 1; g < 16; ++g) m = fmaxf(m, red[g * 20 + t]);
    mcol[t] = m;
  }
  __syncthreads();
  {
    const float mj = mcol[jl];
    float s = 0.f;
#pragma unroll
    for (int i = 0; i < 8; ++i) s += expf(Ss[(grp * 8 + i) * 20 + jl] - mj);
    red[grp * 20 + jl] = s;
  }
  __syncthreads();
  if (t < 16) {
    float s = red[t];
#pragma unroll
    for (int g = 1; g < 16; ++g) s += red[g * 20 + t];
    scol[t] = 1.f / s;
  }
  __syncthreads();
  {  // normalized attn -> As[j][i] (LDS, no global round-trip)
    const int il = t & 31, jg = t >> 5;
#pragma unroll
    for (int rep = 0; rep < 2; ++rep) {
      const int j2 = jg + rep * 8;
      const float mj = mcol[j2], is = scol[j2];
#pragma unroll
      for (int c4 = 0; c4 < 4; ++c4) {
        const int i = il + c4 * 32;
        As[j2 * 132 + i] = expf(Ss[i * 20 + j2] - mj) * is;
      }
    }
  }
  __syncthreads();
  // ---- meanlog phase: ML[b][j0g+j][:] = sum_i As[j][i] * logV[b][i][:] ----
  const float* logV = P + ((size_t)2 * kNMAT + (size_t)b * kM) * kMSZ;
  const int d0 = t * 4;
  float mlacc[16][4] = {};
  for (int k = 0; k < kM; k += 4) {
    float4 vr[4];
#pragma unroll
    for (int kk = 0; kk < 4; ++kk)
      vr[kk] = CF4(&logV[(size_t)(k + kk) * kMSZ + d0]);
#pragma unroll
    for (int j = 0; j < 16; ++j) {
      const float4 w = CF4(&As[j * 132 + k]);
      const float wv[4] = {w.x, w.y, w.z, w.w};
#pragma unroll
      for (int kk = 0; kk < 4; ++kk) {
        const float* vv = (const float*)&vr[kk];
#pragma unroll
        for (int dd = 0; dd < 4; ++dd)
          mlacc[j][dd] = fmaf(wv[kk], vv[dd], mlacc[j][dd]);
      }
    }
  }
#pragma unroll
  for (int j = 0; j < 16; ++j)
    F4(&ML[((size_t)b * kM + j0g + j) * kMSZ + d0]) =
        make_float4(mlacc[j][0], mlacc[j][1], mlacc[j][2], mlacc[j][3]);
}

// ------------------------------------------------------------------ exp ----
// out = exp(S): scaling-and-squaring + degree-7 Horner Taylor (||M||<=0.5
// after scaling -> truncation 1.6e-7, invisible vs the 0.0039 floor).
// 4 waves/block, one matrix per wave, private LDS slot, no s_barrier.
// M and T are SYMMETRIC, so row-fragments load as b128 from [k][r].
constexpr int kESlot = 2 * 1152;  // Mb + Tb

__global__ __launch_bounds__(256) void k_expm(const float* __restrict__ ML,
                                              float* __restrict__ out) {
  __shared__ float lds[4 * kESlot];
  const int t = threadIdx.x;
  const int wid = t >> 6, lane = t & 63;
  const size_t bm = (size_t)blockIdx.x * 4 + wid;
  float* Mb = lds + wid * kESlot;
  float* Tb = Mb + 1152;
  const float* S = ML + bm * kMSZ;
  const int r = lane >> 1, c0 = (lane & 1) * 16;
  float4 v0 = CF4(S + r * 32 + c0),     v1 = CF4(S + r * 32 + c0 + 4),
         v2 = CF4(S + r * 32 + c0 + 8), v3 = CF4(S + r * 32 + c0 + 12);
  float lsum = v0.x*v0.x + v0.y*v0.y + v0.z*v0.z + v0.w*v0.w
             + v1.x*v1.x + v1.y*v1.y + v1.z*v1.z + v1.w*v1.w
             + v2.x*v2.x + v2.y*v2.y + v2.z*v2.z + v2.w*v2.w
             + v3.x*v3.x + v3.y*v3.y + v3.z*v3.z + v3.w*v3.w;
#pragma unroll
  for (int d = 1; d < 64; d <<= 1) lsum += __shfl_xor(lsum, d);
  const float fn = sqrtf(lsum);     // Frobenius norm >= spectral norm
  int sc = 0;
  if (fn > 0.5f) sc = (int)ceilf(log2f(fn * 2.0f));
  const float scale = exp2f((float)(-sc));
  v0.x*=scale; v0.y*=scale; v0.z*=scale; v0.w*=scale;
  v1.x*=scale; v1.y*=scale; v1.z*=scale; v1.w*=scale;
  v2.x*=scale; v2.y*=scale; v2.z*=scale; v2.w*=scale;
  v3.x*=scale; v3.y*=scale; v3.z*=scale; v3.w*=scale;
  F4(&Mb[r * 36 + c0])      = v0;
  F4(&Mb[r * 36 + c0 + 4])  = v1;
  F4(&Mb[r * 36 + c0 + 8])  = v2;
  F4(&Mb[r * 36 + c0 + 12]) = v3;
  __builtin_amdgcn_wave_barrier();
  const int rr = (lane >> 3) * 4, cc = (lane & 7) * 4;
#pragma unroll
  for (int i = 0; i < 4; ++i) {  // T = I + M/7
    float4 v = F4(&Mb[(rr + i) * 36 + cc]);
    v.x = v.x * (1.f/7.f) + ((rr + i == cc + 0) ? 1.f : 0.f);
    v.y = v.y * (1.f/7.f) + ((rr + i == cc + 1) ? 1.f : 0.f);
    v.z = v.z * (1.f/7.f) + ((rr + i == cc + 2) ? 1.f : 0.f);
    v.w = v.w * (1.f/7.f) + ((rr + i == cc + 3) ? 1.f : 0.f);
    F4(&Tb[(rr + i) * 36 + cc]) = v;
  }
  __builtin_amdgcn_wave_barrier();
  for (int j = 6; j >= 1; --j) {  // T <- I + (M*T)/j, in place
    float a4[4][4] = {};
    for (int k = 0; k < 32; ++k) {
      const float4 mv = CF4(&Mb[k * 36 + rr]);  // M[rr..rr+3][k] by symmetry
      const float mvv[4] = {mv.x, mv.y, mv.z, mv.w};
      const float4 tv = CF4(&Tb[k * 36 + cc]);
      const float tvv[4] = {tv.x, tv.y, tv.z, tv.w};
#pragma unroll
      for (int i = 0; i < 4; ++i)
#pragma unroll
        for (int j2 = 0; j2 < 4; ++j2) a4[i][j2] += mvv[i] * tvv[j2];
    }
    const float inv = 1.f / (float)j;
#pragma unroll
    for (int i = 0; i < 4; ++i) {
      float4 v;
      v.x = a4[i][0] * inv + ((rr + i == cc + 0) ? 1.f : 0.f);
      v.y = a4[i][1] * inv + ((rr + i == cc + 1) ? 1.f : 0.f);
      v.z = a4[i][2] * inv + ((rr + i == cc + 2) ? 1.f : 0.f);
      v.w = a4[i][3] * inv + ((rr + i == cc + 3) ? 1.f : 0.f);
      F4(&Tb[(rr + i) * 36 + cc]) = v;
    }
    __builtin_amdgcn_wave_barrier();
  }
  for (int st = 0; st < sc; ++st) {  // T <- T*T, in place (T symmetric)
    float a4[4][4] = {};
    for (int k = 0; k < 32; ++k) {
      const float4 mv = CF4(&Tb[k * 36 + rr]);  // T[rr..rr+3][k] by symmetry
      const float mvv[4] = {mv.x, mv.y, mv.z, mv.w};
      const float4 tv = CF4(&Tb[k * 36 + cc]);
      const float tvv[4] = {tv.x, tv.y, tv.z, tv.w};
#pragma unroll
      for (int i = 0; i < 4; ++i)
#pragma unroll
        for (int j2 = 0; j2 < 4; ++j2) a4[i][j2] += mvv[i] * tvv[j2];
    }
#pragma unroll
    for (int i = 0; i < 4; ++i)
      F4(&Tb[(rr + i) * 36 + cc]) =
          make_float4(a4[i][0], a4[i][1], a4[i][2], a4[i][3]);
    __builtin_amdgcn_wave_barrier();
  }
#pragma unroll
  for (int i = 0; i < 4; ++i) {
    const float4 v = CF4(&Tb[(rr + i) * 36 + cc]);
    F4(&out[bm * kMSZ + (rr + i) * 32 + cc]) = v;
  }
}

// -------------------------------------------------------------- launch ----
extern "C" void kernel_launch(void* const* d_in, const int* in_sizes, int n_in,
                              void* d_out, int out_size, void* d_ws, size_t ws_size,
                              hipStream_t stream) {
  const float* x  = (const float*)d_in[0];
  const float* Wq = (const float*)d_in[1];
  const float* Wk = (const float*)d_in[2];
  const float* Wv = (const float*)d_in[3];
  float* ws   = (float*)d_ws;
  float* P    = ws;                 // [3][4096][1024]
  float* sq   = ws + OFF_SS;        // [3][4096]
  float* ML   = ws;                 // reuse logQ region (dead after attn phase)
  float* out  = (float*)d_out;

  k_bimap<<<kNMAT, 256, 0, stream>>>(x, Wq, Wk, Wv, P);
  k_jacobi_log<<<3 * kNMAT / 8, 256, 0, stream>>>(P, sq);
  k_attn_meanlog<<<dim3(8, kBS), 256, 0, stream>>>(P, sq, ML);
  k_expm<<<kNMAT / 4, 256, 0, stream>>>(ML, out);
}